// Round 16
// 4003.162 us; speedup vs baseline: 5.7479x; 1.0385x over previous
//
#include <hip/hip_runtime.h>
#include <hip/hip_bf16.h>
#include <math.h>

#define PAD_ID 0
#define UNK_ID 1
#define START_ID 2
#define END_ID 3

constexpr int B = 16, S = 512, T = 128, V = 32000, E = 128, H = 256, D = 512;
constexpr int C3 = 1536;        // 3*D
constexpr int VO = 31997;       // V-3
constexpr int JS = 32000;       // padded col count for outT2

typedef short short8 __attribute__((ext_vector_type(8)));
typedef float f32x4 __attribute__((ext_vector_type(4)));

__device__ __forceinline__ float sigm(float x) { return 1.0f / (1.0f + __expf(-x)); }
__device__ __forceinline__ short bf16s(float x) {
    __hip_bfloat16 h = __float2bfloat16(x);
    return *reinterpret_cast<short*>(&h);
}

__device__ __forceinline__ uint4 cloadu4(const uint* p) {
    uint4 v;
    asm volatile("global_load_dwordx4 %0, %1, off sc0 sc1" : "=v"(v) : "v"(p));
    return v;
}
__device__ __forceinline__ void pstore(uint* p, uint v) {
    __hip_atomic_store(p, v, __ATOMIC_RELAXED, __HIP_MEMORY_SCOPE_AGENT);
}

__device__ __forceinline__ void gload_lds16(const void* g, void* l) {
    __builtin_amdgcn_global_load_lds(
        (const __attribute__((address_space(1))) void*)(g),
        (__attribute__((address_space(3))) void*)(l), 16, 0, 0);
}

__device__ __forceinline__ void st_bf8(ushort* dst, float4 a, float4 b) {
    short8 o;
    o[0] = bf16s(a.x); o[1] = bf16s(a.y); o[2] = bf16s(a.z); o[3] = bf16s(a.w);
    o[4] = bf16s(b.x); o[5] = bf16s(b.y); o[6] = bf16s(b.z); o[7] = bf16s(b.w);
    *(short8*)dst = o;
}

// ---------------- poll 16 packets tagged e; write 16 bf16 to dst
__device__ __forceinline__ void poll_stage16(const uint* src, uint e, ushort* dst) {
    uint4 a0, a1, a2, a3;
    for (;;) {
        a0 = cloadu4(src); a1 = cloadu4(src + 4); a2 = cloadu4(src + 8); a3 = cloadu4(src + 12);
        asm volatile("s_waitcnt vmcnt(0)" ::: "memory");
        __builtin_amdgcn_sched_barrier(0);
        uint d = (a0.x ^ e) | (a0.y ^ e) | (a0.z ^ e) | (a0.w ^ e)
               | (a1.x ^ e) | (a1.y ^ e) | (a1.z ^ e) | (a1.w ^ e)
               | (a2.x ^ e) | (a2.y ^ e) | (a2.z ^ e) | (a2.w ^ e)
               | (a3.x ^ e) | (a3.y ^ e) | (a3.z ^ e) | (a3.w ^ e);
        if ((d & 0xffffu) == 0) break;
        __builtin_amdgcn_s_sleep(1);
    }
    short8 o0, o1;
    o0[0] = (short)(a0.x >> 16); o0[1] = (short)(a0.y >> 16); o0[2] = (short)(a0.z >> 16); o0[3] = (short)(a0.w >> 16);
    o0[4] = (short)(a1.x >> 16); o0[5] = (short)(a1.y >> 16); o0[6] = (short)(a1.z >> 16); o0[7] = (short)(a1.w >> 16);
    o1[0] = (short)(a2.x >> 16); o1[1] = (short)(a2.y >> 16); o1[2] = (short)(a2.z >> 16); o1[3] = (short)(a2.w >> 16);
    o1[4] = (short)(a3.x >> 16); o1[5] = (short)(a3.y >> 16); o1[6] = (short)(a3.z >> 16); o1[7] = (short)(a3.w >> 16);
    *(short8*)dst = o0;
    *(short8*)(dst + 8) = o1;
}

// ---------------- poll 32 packets tagged e; write 32 bf16 to dst
__device__ __forceinline__ void poll_stage32(const uint* src, uint e, ushort* dst) {
    uint4 a[8];
    for (;;) {
#pragma unroll
        for (int i = 0; i < 8; i++) a[i] = cloadu4(src + i * 4);
        asm volatile("s_waitcnt vmcnt(0)" ::: "memory");
        __builtin_amdgcn_sched_barrier(0);
        uint d = 0;
#pragma unroll
        for (int i = 0; i < 8; i++)
            d |= (a[i].x ^ e) | (a[i].y ^ e) | (a[i].z ^ e) | (a[i].w ^ e);
        if ((d & 0xffffu) == 0) break;
        __builtin_amdgcn_s_sleep(1);
    }
#pragma unroll
    for (int i = 0; i < 8; i += 2) {
        short8 o;
        o[0] = (short)(a[i].x >> 16);     o[1] = (short)(a[i].y >> 16);
        o[2] = (short)(a[i].z >> 16);     o[3] = (short)(a[i].w >> 16);
        o[4] = (short)(a[i + 1].x >> 16); o[5] = (short)(a[i + 1].y >> 16);
        o[6] = (short)(a[i + 1].z >> 16); o[7] = (short)(a[i + 1].w >> 16);
        *(short8*)(dst + i * 4) = o;
    }
}

// ---------------- weight packing: W[4H][K] -> P[k][u] = float4 of 4 gates
__global__ void pack4_kernel(const float* __restrict__ W, float4* __restrict__ P, int Hn, int K) {
    int i = blockIdx.x * blockDim.x + threadIdx.x;
    if (i >= K * Hn) return;
    int k = i / Hn, u = i - k * Hn;
    float4 v;
    v.x = W[(size_t)(0 * Hn + u) * K + k];
    v.y = W[(size_t)(1 * Hn + u) * K + k];
    v.z = W[(size_t)(2 * Hn + u) * K + k];
    v.w = W[(size_t)(3 * Hn + u) * K + k];
    P[(size_t)k * Hn + u] = v;
}

// ---------------- MFMA-row pack (H=256 outputs): row = (u>>3)*32 + g*8 + (u&7)
__global__ void packencMK_k(const float* __restrict__ W, ushort* __restrict__ P, int K) {
    int i = blockIdx.x * blockDim.x + threadIdx.x;
    if (i >= 4 * H * K) return;
    int k = i % K, row = i / K;
    int g = (row >> 3) & 3, ul = row & 7, uh = row >> 5;
    int u = uh * 8 + ul;
    P[i] = (ushort)bf16s(W[(size_t)(g * H + u) * K + k]);
}

// ---------------- decoder W0 pack for MFMA (row = bk*64 + g*16 + u%16)
__global__ void packdecM_k(const float* __restrict__ W, ushort* __restrict__ P) {
    int i = blockIdx.x * blockDim.x + threadIdx.x;
    if (i >= 4 * D * D) return;
    int k = i & 511, row = i >> 9;
    int g = (row >> 4) & 3, u = (row >> 6) * 16 + (row & 15);
    P[i] = (ushort)bf16s(W[(size_t)(g * D + u) * D + k]);
}

// ---------------- decoder layer1 pack: [W1i | W1h] -> PM1[row][1024] bf16
__global__ void packdecM2_k(const float* __restrict__ Wi, const float* __restrict__ Wh,
                            ushort* __restrict__ P) {
    int i = blockIdx.x * blockDim.x + threadIdx.x;
    if (i >= 4 * D * D * 2) return;
    int k = i & 1023, row = i >> 10;
    int g = (row >> 4) & 3, u = (row >> 6) * 16 + (row & 15);
    float v = (k < 512) ? Wi[(size_t)(g * D + u) * D + k]
                        : Wh[(size_t)(g * D + u) * D + (k - 512)];
    P[i] = (ushort)bf16s(v);
}

// ---------------- encoder layer-0 gates, tiled (8 rows/block). grid S*B/8, 256 thr.
__global__ void enc0_gates2(const int* __restrict__ ids, const float* __restrict__ emb,
                            const float4* __restrict__ Pf, const float* __restrict__ bf_,
                            const float4* __restrict__ Pb, const float* __restrict__ bb_,
                            float* __restrict__ Gf, float* __restrict__ Gb) {
    int n0 = blockIdx.x * 8;
    int u = threadIdx.x;
    __shared__ float xr[8][E];
    for (int i = u; i < 8 * E; i += 256) {
        int r = i >> 7, e = i & 127;
        int n = n0 + r, s = n / B, b = n - s * B;
        int tok = ids[b * S + s];
        if (tok >= V) tok = UNK_ID;
        xr[r][e] = emb[(size_t)tok * E + e];
    }
    __syncthreads();
#pragma unroll
    for (int dir = 0; dir < 2; dir++) {
        const float4* P = dir ? Pb : Pf;
        const float* bs = dir ? bb_ : bf_;
        float* G = dir ? Gb : Gf;
        float acc[8][4];
#pragma unroll
        for (int r = 0; r < 8; r++)
#pragma unroll
            for (int g = 0; g < 4; g++) acc[r][g] = 0.f;
#pragma unroll 4
        for (int k = 0; k < E; k++) {
            float4 w = P[k * H + u];
#pragma unroll
            for (int r = 0; r < 8; r++) {
                float x = xr[r][k];
                acc[r][0] += x * w.x; acc[r][1] += x * w.y;
                acc[r][2] += x * w.z; acc[r][3] += x * w.w;
            }
        }
        float b0 = bs[u], b1 = bs[H + u], b2 = bs[2 * H + u], b3 = bs[3 * H + u];
#pragma unroll
        for (int r = 0; r < 8; r++) {
            float* g = G + (size_t)(n0 + r) * (4 * H);
            g[u] = acc[r][0] + b0; g[H + u] = acc[r][1] + b1;
            g[2 * H + u] = acc[r][2] + b2; g[3 * H + u] = acc[r][3] + b3;
        }
    }
}

// ---------------- encoder layer-1 gates via MFMA. grid 256, 256 thr.
__global__ void __launch_bounds__(256) enc1g_mfma(
        const float* __restrict__ h0f, const float* __restrict__ h0b,
        const ushort* __restrict__ PMf, const ushort* __restrict__ PMb,
        const float* __restrict__ bf_, const float* __restrict__ bb_,
        float* __restrict__ Gf, float* __restrict__ Gb) {
    __shared__ __align__(16) ushort X[16 * 520];
    __shared__ float gs[4][32][17];
    __shared__ float bias_s[128];
    int bid = blockIdx.x;
    int dirb = (bid >> 3) & 1, bk = bid & 7, ns = bid >> 4;
    const ushort* PM = dirb ? PMb : PMf;
    const float* bs = dirb ? bb_ : bf_;
    float* G = dirb ? Gb : Gf;
    int tid = threadIdx.x;
    int lane = tid & 63, w = tid >> 6;
    int cl = lane & 15, hi = lane >> 4;

    short8 afr[2][16];
    {
        int rowbase = (bk * 4 + w) * 32;
#pragma unroll
        for (int mt = 0; mt < 2; mt++)
#pragma unroll
            for (int kt = 0; kt < 16; kt++)
                afr[mt][kt] = *(const short8*)(PM + (size_t)(rowbase + mt * 16 + cl) * 512 + kt * 32 + hi * 8);
    }
    if (tid < 128) {
        int g = (tid >> 3) & 3;
        int u = (bk * 4 + (tid >> 5)) * 8 + (tid & 7);
        bias_s[tid] = bs[g * H + u];
    }
    int nl = tid >> 4, kseg = tid & 15;
    int en = tid & 15, rgrp = tid >> 4;
    for (int tt = 0; tt < 32; tt++) {
        int nt = ns * 32 + tt;
        __syncthreads();
        {
            int n = nt * 16 + nl;
            const float* src = (kseg < 8) ? (h0f + (size_t)n * H + kseg * 32)
                                          : (h0b + (size_t)n * H + (kseg - 8) * 32);
            float4 v0 = *(const float4*)(src), v1 = *(const float4*)(src + 4);
            float4 v2 = *(const float4*)(src + 8), v3 = *(const float4*)(src + 12);
            float4 v4 = *(const float4*)(src + 16), v5 = *(const float4*)(src + 20);
            float4 v6 = *(const float4*)(src + 24), v7 = *(const float4*)(src + 28);
            ushort* dst = X + nl * 520 + kseg * 32;
            st_bf8(dst, v0, v1); st_bf8(dst + 8, v2, v3);
            st_bf8(dst + 16, v4, v5); st_bf8(dst + 24, v6, v7);
        }
        __syncthreads();
        {
            f32x4 acc0 = {0.f, 0.f, 0.f, 0.f}, acc1 = {0.f, 0.f, 0.f, 0.f};
            const ushort* hp = X + cl * 520 + hi * 8;
#pragma unroll
            for (int kt = 0; kt < 16; kt++) {
                short8 bfr = *(const short8*)(hp + kt * 32);
                acc0 = __builtin_amdgcn_mfma_f32_16x16x32_bf16(afr[0][kt], bfr, acc0, 0, 0, 0);
                acc1 = __builtin_amdgcn_mfma_f32_16x16x32_bf16(afr[1][kt], bfr, acc1, 0, 0, 0);
            }
#pragma unroll
            for (int i = 0; i < 4; i++) {
                gs[w][hi * 4 + i][cl] = acc0[i];
                gs[w][16 + hi * 4 + i][cl] = acc1[i];
            }
        }
        __syncthreads();
        {
            int wv = rgrp >> 2, g = rgrp & 3;
            int u0 = (bk * 4 + wv) * 8;
            float* dst = G + (size_t)(nt * 16 + en) * 1024 + g * 256 + u0;
            float4 o0, o1;
            o0.x = gs[wv][g * 8 + 0][en] + bias_s[rgrp * 8 + 0];
            o0.y = gs[wv][g * 8 + 1][en] + bias_s[rgrp * 8 + 1];
            o0.z = gs[wv][g * 8 + 2][en] + bias_s[rgrp * 8 + 2];
            o0.w = gs[wv][g * 8 + 3][en] + bias_s[rgrp * 8 + 3];
            o1.x = gs[wv][g * 8 + 4][en] + bias_s[rgrp * 8 + 4];
            o1.y = gs[wv][g * 8 + 5][en] + bias_s[rgrp * 8 + 5];
            o1.z = gs[wv][g * 8 + 6][en] + bias_s[rgrp * 8 + 6];
            o1.w = gs[wv][g * 8 + 7][en] + bias_s[rgrp * 8 + 7];
            *(float4*)dst = o0;
            *(float4*)(dst + 4) = o1;
        }
    }
}

// ================= device bodies =================

// ---- enc scan body (dataflow packets). blk in [0,16).
__device__ __forceinline__ void enc_scan_body(int blk, char* smem,
        const float* __restrict__ Gf, const float* __restrict__ Gb,
        const ushort* __restrict__ PMf, const ushort* __restrict__ PMb,
        float* __restrict__ hof, float* __restrict__ hob,
        float* __restrict__ hfin, uint* __restrict__ pk) {
    ushort* hh = (ushort*)smem;
    float (*gs)[32][17] = (float(*)[32][17])(smem + 8448);
    int dirb = blk >> 3, bk = blk & 7;
    const float* G = dirb ? Gb : Gf;
    const ushort* PM = dirb ? PMb : PMf;
    float* ho = dirb ? hob : hof;
    int tid = threadIdx.x;
    int lane = tid & 63, w = tid >> 6;
    int cl = lane & 15, hi = lane >> 4;

    short8 afr[2][8];
    {
        int rowbase = (bk * 4 + w) * 32;
#pragma unroll
        for (int mt = 0; mt < 2; mt++)
#pragma unroll
            for (int kt = 0; kt < 8; kt++)
                afr[mt][kt] = *(const short8*)(PM + (size_t)(rowbase + mt * 16 + cl) * 256 + kt * 32 + hi * 8);
    }
    int ub = tid & 31, bb = tid >> 5;
    int u_glob = bk * 32 + ub;
    int gsw = ub >> 3, ul = ub & 7;
    float c_a = 0.f, c_b = 0.f;
    int b0s = tid >> 4, u0s = (tid & 15) * 16;

    for (int step = 0; step < S; step++) {
        int s = dirb ? (S - 1 - step) : step;
        int cur = step & 1;
        const float* gA = G + ((size_t)(s * B + bb)) * 1024 + u_glob;
        const float* gB = G + ((size_t)(s * B + bb + 8)) * 1024 + u_glob;
        float pa0 = gA[0], pa1 = gA[256], pa2 = gA[512], pa3 = gA[768];
        float pb0 = gB[0], pb1 = gB[256], pb2 = gB[512], pb3 = gB[768];
        poll_stage16(pk + cur * 8192 + dirb * 4096 + tid * 16,
                     (uint)step & 0xffffu, hh + b0s * 264 + u0s);
        __syncthreads();
        {
            f32x4 acc0 = {0.f, 0.f, 0.f, 0.f}, acc1 = {0.f, 0.f, 0.f, 0.f};
            const ushort* hp = hh + cl * 264 + hi * 8;
#pragma unroll
            for (int kt = 0; kt < 8; kt++) {
                short8 bfr = *(const short8*)(hp + kt * 32);
                acc0 = __builtin_amdgcn_mfma_f32_16x16x32_bf16(afr[0][kt], bfr, acc0, 0, 0, 0);
                acc1 = __builtin_amdgcn_mfma_f32_16x16x32_bf16(afr[1][kt], bfr, acc1, 0, 0, 0);
            }
#pragma unroll
            for (int i = 0; i < 4; i++) {
                gs[w][hi * 4 + i][cl] = acc0[i];
                gs[w][16 + hi * 4 + i][cl] = acc1[i];
            }
        }
        __syncthreads();
        {
            float q0 = gs[gsw][0 + ul][bb];
            float q1 = gs[gsw][8 + ul][bb];
            float q2 = gs[gsw][16 + ul][bb];
            float q3 = gs[gsw][24 + ul][bb];
            float ig = sigm(pa0 + q0), fg = sigm(pa1 + q1), gt = tanhf(pa2 + q2), og = sigm(pa3 + q3);
            c_a = fg * c_a + ig * gt;
            float hA = og * tanhf(c_a);
            q0 = gs[gsw][0 + ul][bb + 8];
            q1 = gs[gsw][8 + ul][bb + 8];
            q2 = gs[gsw][16 + ul][bb + 8];
            q3 = gs[gsw][24 + ul][bb + 8];
            ig = sigm(pb0 + q0); fg = sigm(pb1 + q1); gt = tanhf(pb2 + q2); og = sigm(pb3 + q3);
            c_b = fg * c_b + ig * gt;
            float hB = og * tanhf(c_b);
            uint tg = (uint)(step + 1) & 0xffffu;
            uint* dstp = pk + (cur ^ 1) * 8192 + dirb * 4096;
            pstore(&dstp[bb * 256 + u_glob], ((uint)(ushort)bf16s(hA) << 16) | tg);
            pstore(&dstp[(bb + 8) * 256 + u_glob], ((uint)(ushort)bf16s(hB) << 16) | tg);
            ho[((size_t)(s * B + bb)) * H + u_glob] = hA;
            ho[((size_t)(s * B + bb + 8)) * H + u_glob] = hB;
            if (step == S - 1) {
                hfin[bb * (2 * H) + dirb * H + u_glob] = hA;
                hfin[(bb + 8) * (2 * H) + dirb * H + u_glob] = hB;
            }
        }
    }
}

// ---- dec0 gates body
__device__ __forceinline__ void dec0_body(int bid, char* smem,
        const int* __restrict__ tgt, const float* __restrict__ emb,
        const float4* __restrict__ P, const float* __restrict__ bias,
        float* __restrict__ G) {
    float (*xr)[E] = (float(*)[E])smem;
    int n0 = bid * 8;
    int tid = threadIdx.x;
    for (int i = tid; i < 8 * E; i += 256) {
        int r = i >> 7, e = i & 127;
        int n = n0 + r, t = n / B, b = n - t * B;
        int tok;
        if (t == 0) tok = START_ID;
        else { tok = tgt[b * T + (t - 1)]; if (tok >= V) tok = UNK_ID; }
        xr[r][e] = emb[(size_t)tok * E + e];
    }
    __syncthreads();
#pragma unroll
    for (int half = 0; half < 2; half++) {
        int u = tid + half * 256;
        float acc[8][4];
#pragma unroll
        for (int r = 0; r < 8; r++)
#pragma unroll
            for (int g = 0; g < 4; g++) acc[r][g] = 0.f;
#pragma unroll 4
        for (int k = 0; k < E; k++) {
            float4 w = P[k * D + u];
#pragma unroll
            for (int r = 0; r < 8; r++) {
                float x = xr[r][k];
                acc[r][0] += x * w.x; acc[r][1] += x * w.y;
                acc[r][2] += x * w.z; acc[r][3] += x * w.w;
            }
        }
        float b0 = bias[u], b1 = bias[D + u], b2 = bias[2 * D + u], b3 = bias[3 * D + u];
#pragma unroll
        for (int r = 0; r < 8; r++) {
            float* g = G + (size_t)(n0 + r) * (4 * D);
            g[u] = acc[r][0] + b0; g[D + u] = acc[r][1] + b1;
            g[2 * D + u] = acc[r][2] + b2; g[3 * D + u] = acc[r][3] + b3;
        }
    }
}

// ---- dec scan body (dataflow). blk in [0,32).
__device__ __forceinline__ void dec_body(int bk, char* smem,
        const float* __restrict__ G0, const ushort* __restrict__ PM0,
        const ushort* __restrict__ PM1, const float* __restrict__ b1,
        uint* __restrict__ h0pk, uint* __restrict__ h1pk,
        float* __restrict__ h1out) {
    ushort* hb = (ushort*)smem;
    float (*gs)[16][17] = (float(*)[16][17])(smem + 33024);
    int tid = threadIdx.x;
    int lane = tid & 63, w = tid >> 6;
    int cl = lane & 15, hi = lane >> 4;

    short8 a0[16], a1[32];
    {
        const ushort* base0 = PM0 + (size_t)(bk * 64 + w * 16 + cl) * 512 + hi * 8;
#pragma unroll
        for (int kt = 0; kt < 16; kt++) a0[kt] = *(const short8*)(base0 + kt * 32);
        const ushort* base1 = PM1 + (size_t)(bk * 64 + w * 16 + cl) * 1024 + hi * 8;
#pragma unroll
        for (int kt = 0; kt < 32; kt++) a1[kt] = *(const short8*)(base1 + kt * 32);
    }
    int u_loc = tid & 15, b = tid >> 4;
    int u = bk * 16 + u_loc;
    float bi0 = b1[u], bi1 = b1[512 + u], bi2 = b1[1024 + u], bi3 = b1[1536 + u];
    float c0v = 0.f, c1v = 0.f;
    int sb = tid >> 4, kseg = tid & 15;
    int sflat = sb * 512 + kseg * 32;

    for (int t = 0; t < T; t++) {
        int cur = t & 1;
        poll_stage32(h0pk + ((t + 1) & 1) * 8192 + sflat, (uint)(t + 1) & 0xffffu,
                     hb + sb * 1032 + kseg * 32);
        __syncthreads();
        {
            f32x4 acc = {0.f, 0.f, 0.f, 0.f};
            const ushort* hp = hb + cl * 1032 + hi * 8;
#pragma unroll
            for (int kt = 0; kt < 16; kt++) {
                short8 bfr = *(const short8*)(hp + kt * 32);
                acc = __builtin_amdgcn_mfma_f32_16x16x32_bf16(a0[kt], bfr, acc, 0, 0, 0);
            }
#pragma unroll
            for (int i = 0; i < 4; i++) gs[w][hi * 4 + i][cl] = acc[i];
        }
        __syncthreads();
        {
            const float* gg = G0 + ((size_t)(t * B + b)) * 2048 + u;
            float g0 = gg[0]    + gs[0][u_loc][b];
            float g1 = gg[512]  + gs[1][u_loc][b];
            float g2 = gg[1024] + gs[2][u_loc][b];
            float g3 = gg[1536] + gs[3][u_loc][b];
            float ig = sigm(g0), fg = sigm(g1), gt = tanhf(g2), og = sigm(g3);
            c0v = fg * c0v + ig * gt;
            float h0n = og * tanhf(c0v);
            pstore(&h0pk[cur * 8192 + b * 512 + u],
                   ((uint)(ushort)bf16s(h0n) << 16) | ((uint)(t + 2) & 0xffffu));
        }
        poll_stage32(h0pk + cur * 8192 + sflat, (uint)(t + 2) & 0xffffu,
                     hb + sb * 1032 + kseg * 32);
        poll_stage32(h1pk + ((t + 1) & 1) * 8192 + sflat, (uint)(t + 1) & 0xffffu,
                     hb + sb * 1032 + 512 + kseg * 32);
        __syncthreads();
        {
            f32x4 acc = {0.f, 0.f, 0.f, 0.f};
            const ushort* hp = hb + cl * 1032 + hi * 8;
#pragma unroll
            for (int kt = 0; kt < 32; kt++) {
                short8 bfr = *(const short8*)(hp + kt * 32);
                acc = __builtin_amdgcn_mfma_f32_16x16x32_bf16(a1[kt], bfr, acc, 0, 0, 0);
            }
#pragma unroll
            for (int i = 0; i < 4; i++) gs[w][hi * 4 + i][cl] = acc[i];
        }
        __syncthreads();
        {
            float g0 = bi0 + gs[0][u_loc][b];
            float g1 = bi1 + gs[1][u_loc][b];
            float g2 = bi2 + gs[2][u_loc][b];
            float g3 = bi3 + gs[3][u_loc][b];
            float ig = sigm(g0), fg = sigm(g1), gt = tanhf(g2), og = sigm(g3);
            c1v = fg * c1v + ig * gt;
            float h1n = og * tanhf(c1v);
            pstore(&h1pk[cur * 8192 + b * 512 + u],
                   ((uint)(ushort)bf16s(h1n) << 16) | ((uint)(t + 2) & 0xffffu));
            h1out[((size_t)(t * B + b)) * 512 + u] = h1n;
        }
        __syncthreads();
    }
}

// ---- enchB pack: [b][o(d/8)=64][s(512)][8d]
__device__ __forceinline__ void encht2_body(int bid,
        const float* __restrict__ h1f, const float* __restrict__ h1b,
        ushort* __restrict__ enchB) {
    int idx = bid * 256 + threadIdx.x;
    int b = idx >> 15;
    int r = idx & 32767;
    int o = r >> 9, s = r & 511;
    const float* src = (o < 32) ? (h1f + ((size_t)(s * B + b)) * H + o * 8)
                                : (h1b + ((size_t)(s * B + b)) * H + (o - 32) * 8);
    float4 v0 = *(const float4*)src, v1 = *(const float4*)(src + 4);
    st_bf8(enchB + ((size_t)b << 18) + o * 4096 + s * 8, v0, v1);
}

// ---- enchT pack: [b][o(s/8)=64][d(512)][8s]
__device__ __forceinline__ void encht2T_body(int bid,
        const float* __restrict__ h1f, const float* __restrict__ h1b,
        ushort* __restrict__ enchT) {
    int idx = bid * 256 + threadIdx.x;
    int b = idx >> 15;
    int r = idx & 32767;
    int o = r >> 9, d = r & 511;
    float f[8];
#pragma unroll
    for (int j = 0; j < 8; j++) {
        int s = o * 8 + j;
        f[j] = (d < H) ? h1f[((size_t)(s * B + b)) * H + d]
                       : h1b[((size_t)(s * B + b)) * H + (d - H)];
    }
    float4 v0 = {f[0], f[1], f[2], f[3]}, v1 = {f[4], f[5], f[6], f[7]};
    st_bf8(enchT + ((size_t)b << 18) + o * 4096 + d * 8, v0, v1);
}

// ---- out_proj body
__device__ __forceinline__ void outproj_body(int bid, char* smem,
        const float* __restrict__ emb, const float* __restrict__ Wvoc,
        __hip_bfloat16* __restrict__ outT2) {
    float (*er)[E + 1] = (float(*)[E + 1])smem;
    int j0 = bid * 32;
    int jl = threadIdx.x & 31, oq = threadIdx.x >> 5;
    for (int i = threadIdx.x; i < 32 * E; i += 256) {
        int jj = i >> 7, e = i & 127;
        int j = j0 + jj;
        er[jj][e] = (j < VO) ? emb[(size_t)(3 + j) * E + e] : 0.f;
    }
    __syncthreads();
    int j = j0 + jl;
#pragma unroll 1
    for (int i = 0; i < 24; i++) {
        int o = oq * 24 + i;
        int k0 = o * 8;
        float acc[8];
#pragma unroll
        for (int kk = 0; kk < 8; kk++) acc[kk] = 0.f;
#pragma unroll 4
        for (int e = 0; e < E; e++) {
            float x = er[jl][e];
            float4 w0 = *(const float4*)(Wvoc + (size_t)e * C3 + k0);
            float4 w1 = *(const float4*)(Wvoc + (size_t)e * C3 + k0 + 4);
            acc[0] += x * w0.x; acc[1] += x * w0.y; acc[2] += x * w0.z; acc[3] += x * w0.w;
            acc[4] += x * w1.x; acc[5] += x * w1.y; acc[6] += x * w1.z; acc[7] += x * w1.w;
        }
        short8 v;
#pragma unroll
        for (int kk = 0; kk < 8; kk++) v[kk] = bf16s(tanhf(acc[kk]));
        *reinterpret_cast<short8*>((char*)outT2 + ((size_t)o * JS + j) * 16) = v;
    }
}

// ---- generic MFMA "A-in-regs @ streamed B" body (FIXED R16: wave-uniform LDS staging).
// NF = #A-frags (K = NF*32). Chunks per tile CH = NF*64, staged in 64-chunk groups:
// group g loaded by wave g%8, LDS dest = Bs + g*64*16 (wave-uniform), chunk = g*64+lane.
template<int NF, int TILES, int OSTR, bool DOEXP>
__device__ __forceinline__ void gemm16_body(char* smem,
        const ushort* __restrict__ Abase, int arow_stride,
        const ushort* __restrict__ Bsrc, float* __restrict__ outbase,
        int out_stride) {
    ushort* Bs = (ushort*)smem;                       // 2 x CH*16 bytes
    const int CH = NF * 64;
    const int NG = CH / 64;                           // 64-chunk groups per tile
    int tid = threadIdx.x;
    int lane = tid & 63, w = tid >> 6;
    int cl = lane & 15, hi = lane >> 4;
    short8 a[NF];
    {
        const ushort* asrc = Abase + (size_t)(w * 16 + cl) * arow_stride + hi * 8;
#pragma unroll
        for (int kt = 0; kt < NF; kt++) a[kt] = *(const short8*)(asrc + kt * 32);
    }
    for (int g = w; g < NG; g += 8) {
        int c = g * 64 + lane;
        int o = c >> 4, jl = c & 15;
        gload_lds16(Bsrc + ((size_t)o * OSTR + jl) * 8,
                    (char*)Bs + (size_t)(g * 64) * 16);
    }
    asm volatile("s_waitcnt vmcnt(0)" ::: "memory");
    __syncthreads();
    int buf = 0;
    for (int t = 0; t < TILES; t++) {
        if (t + 1 < TILES) {
            for (int g = w; g < NG; g += 8) {
                int c = g * 64 + lane;
                int o = c >> 4, jl = c & 15;
                gload_lds16(Bsrc + ((size_t)o * OSTR + (t + 1) * 16 + jl) * 8,
                            (char*)Bs + (size_t)((buf ^ 1) * CH + g * 64) * 16);
            }
        }
        f32x4 acc = {0.f, 0.f, 0.f, 0.f};
        const ushort* bp = Bs + (size_t)buf * CH * 8 + (size_t)(hi * 16 + cl) * 8;
#pragma unroll
        for (int kt = 0; kt < NF; kt++) {
            short8 b = *(const short8*)(bp + (size_t)kt * 512);
            acc = __builtin_amdgcn_mfma_f32_16x16x32_bf16(a[kt], b, acc, 0, 0, 0);
        }
#pragma unroll
        for (int i = 0; i < 4; i++) {
            int row = w * 16 + hi * 4 + i;
            float v = acc[i];
            if (DOEXP) v = __expf(fminf(v, 30.0f));
            outbase[(size_t)row * out_stride + t * 16 + cl] = v;
        }
        asm volatile("s_waitcnt vmcnt(0)" ::: "memory");
        __syncthreads();
        buf ^= 1;
    }
}

// ================= mega-kernels =================

__global__ void __launch_bounds__(256) megaA(
        const float* Gf, const float* Gb, const ushort* PMf, const ushort* PMb,
        float* hof, float* hob, float* hfin, uint* pk,
        const int* tgt, const float* emb, const float4* PdW, const float* dbias,
        float* Gd0) {
    __shared__ __align__(16) char smem[17152];
    int blk = blockIdx.x;
    if (blk < 16) enc_scan_body(blk, smem, Gf, Gb, PMf, PMb, hof, hob, hfin, pk);
    else dec0_body(blk - 16, smem, tgt, emb, PdW, dbias, Gd0);
}

__global__ void __launch_bounds__(256) enc_pscan3(
        const float* Gf, const float* Gb, const ushort* PMf, const ushort* PMb,
        float* hof, float* hob, float* hfin, uint* pk) {
    __shared__ __align__(16) char smem[17152];
    enc_scan_body(blockIdx.x, smem, Gf, Gb, PMf, PMb, hof, hob, hfin, pk);
}

// megaC: 0..31 dec scan; 32..2079 enchB; 2080..4127 enchT; 4128..5127 outproj.
__global__ void __launch_bounds__(256) megaC(
        const float* G0, const ushort* PM0, const ushort* PM1, const float* b1,
        uint* h0pk, uint* h1pk, float* h1out,
        const float* h1f, const float* h1b, ushort* enchB, ushort* enchT,
        const float* emb, const float* Wvoc, __hip_bfloat16* outT2) {
    __shared__ __align__(16) char smem[37376];
    int blk = blockIdx.x;
    if (blk < 32) dec_body(blk, smem, G0, PM0, PM1, b1, h0pk, h1pk, h1out);
    else if (blk < 2080) encht2_body(blk - 32, h1f, h1b, enchB);
    else if (blk < 4128) encht2T_body(blk - 2080, h1f, h1b, enchT);
    else outproj_body(blk - 4128, smem, emb, Wvoc, outT2);
}

// ---------------- decoder init packets
__global__ void dec_initpk(const float* __restrict__ hinit,
                           uint* __restrict__ h0pk, uint* __restrict__ h1pk) {
    int i = blockIdx.x * blockDim.x + threadIdx.x;
    if (i >= B * D) return;
    pstore(&h0pk[8192 + i], ((uint)(ushort)bf16s(hinit[i]) << 16) | 1u);
    pstore(&h1pk[8192 + i], ((uint)(ushort)bf16s(hinit[B * D + i]) << 16) | 1u);
}

// ---------------- q projections: bf16 qe, bf16 qd, h1dB1 pack. grid T*B, 512 thr.
__global__ void qproj(const float* __restrict__ h1d, const float* __restrict__ Wenc,
                      const float* __restrict__ Wdec, ushort* __restrict__ qeb16,
                      ushort* __restrict__ qdb16, ushort* __restrict__ h1dB1) {
    int n = blockIdx.x;
    int o = threadIdx.x;
    __shared__ float hr[D];
    hr[o] = h1d[(size_t)n * D + o];
    __syncthreads();
    float ae = 0.f, ad = 0.f;
#pragma unroll 4
    for (int k = 0; k < D; k++) {
        float hk = hr[k];
        ae += hk * Wenc[k * D + o];
        ad += hk * Wdec[k * D + o];
    }
    int b = n & 15, t = n >> 4;
    size_t rowb = (size_t)(b * 128 + t) << 9;
    qeb16[rowb + o] = (ushort)bf16s(ae);
    qdb16[rowb + o] = (ushort)bf16s(ad);
    if (o < 64) {
        float4 v0 = *(const float4*)(hr + o * 8);
        float4 v1 = *(const float4*)(hr + o * 8 + 4);
        st_bf8(h1dB1 + ((size_t)b << 16) + o * 1024 + t * 8, v0, v1);
    }
}

// ---------------- h1dB2 pack: [b][o(u/8)=16][d(512)][8u]. grid 512, 256 thr.
__global__ void pack_h1dB2(const float* __restrict__ h1d, ushort* __restrict__ h1dB2) {
    int idx = blockIdx.x * 256 + threadIdx.x;
    int b = idx >> 13;
    int r = idx & 8191;
    int o = r >> 9, d = r & 511;
    float f[8];
#pragma unroll
    for (int j = 0; j < 8; j++)
        f[j] = h1d[((size_t)((o * 8 + j) * B + b)) * D + d];
    float4 v0 = {f[0], f[1], f[2], f[3]}, v1 = {f[4], f[5], f[6], f[7]};
    st_bf8(h1dB2 + ((size_t)b << 16) + o * 4096 + d * 8, v0, v1);
}

// ---------------- scoreAB: blk<16 escore (ew, fused exp); else dec QK^T (dsout).
__global__ void __launch_bounds__(512) scoreAB(
        const ushort* __restrict__ qeb16, const ushort* __restrict__ enchB,
        float* __restrict__ ew,
        const ushort* __restrict__ qdb16, const ushort* __restrict__ h1dB1,
        float* __restrict__ dsout) {
    __shared__ __align__(16) char smem[32768];
    int blk = blockIdx.x;
    if (blk < 16) {
        int b = blk;
        gemm16_body<16, 32, 512, true>(smem,
            qeb16 + ((size_t)(b * 128) << 9), 512,
            enchB + ((size_t)b << 18),
            ew + (size_t)b * T * S, S);
    } else {
        int b = blk - 16;
        gemm16_body<16, 8, 128, false>(smem,
            qdb16 + ((size_t)(b * 128) << 9), 512,
            h1dB1 + ((size_t)b << 16),
            dsout + ((size_t)(b * 128)) * 128, 128);
    }
}

// ---------------- temporal normalization (prefix over t)
__global__ void temporal_k(float* __restrict__ ew) {
    int i = blockIdx.x * blockDim.x + threadIdx.x;
    if (i >= B * S) return;
    int b = i / S, sx = i - b * S;
    float cum = 0.f;
    for (int t = 0; t < T; t++) {
        size_t idx = ((size_t)(b * T + t)) * S + sx;
        float v = ew[idx];
        ew[idx] = v / (t == 0 ? 1.0f : (cum + 1e-8f));
        cum += v;
    }
}

// ---------------- smAB: blk<2048 enc softmax+copy (awb16); else dec softmax (pdb16).
__global__ void __launch_bounds__(512) smAB(
        const float* __restrict__ ew, const int* __restrict__ ids,
        const int* __restrict__ tgt, ushort* __restrict__ awb16,
        float* __restrict__ copyp,
        const float* __restrict__ dsout, ushort* __restrict__ pdb16) {
    __shared__ float red[512];
    int blk = blockIdx.x;
    int tid = threadIdx.x;
    if (blk < 2048) {
        int bt = blk;
        int b = bt >> 7, t = bt & 127;
        float v = ew[(size_t)bt * S + tid];
        int tok = ids[b * S + tid];
        bool pad = (tok == PAD_ID);
        float vm = pad ? -INFINITY : v;
        red[tid] = vm; __syncthreads();
        for (int w = 256; w > 0; w >>= 1) { if (tid < w) red[tid] = fmaxf(red[tid], red[tid + w]); __syncthreads(); }
        float m = red[0]; __syncthreads();
        float ex = pad ? 0.f : __expf(vm - m);
        red[tid] = ex; __syncthreads();
        for (int w = 256; w > 0; w >>= 1) { if (tid < w) red[tid] += red[tid + w]; __syncthreads(); }
        float Z = red[0]; __syncthreads();
        float a = ex / Z;
        int nt = tgt[b * T + t];
        red[tid] = (tok == nt) ? a : 0.f; __syncthreads();
        for (int w = 256; w > 0; w >>= 1) { if (tid < w) red[tid] += red[tid + w]; __syncthreads(); }
        if (tid == 0) copyp[bt] = red[0];
        awb16[(size_t)bt * S + tid] = (ushort)bf16s(a);
    } else {
        int bt2 = blk - 2048;
        int t = bt2 & 127;
        float sc = -INFINITY;
        if (tid < 128 && tid < t) sc = dsout[(size_t)bt2 * 128 + tid];
        if (tid < 128) red[tid] = sc;
        __syncthreads();
        for (int w = 64; w > 0; w >>= 1) { if (tid < w) red[tid] = fmaxf(red[tid], red[tid + w]); __syncthreads(); }
        float m = red[0]; __syncthreads();
        float ex = (tid < 128 && tid < t) ? __expf(sc - m) : 0.f;
        if (tid < 128) red[tid] = ex;
        __syncthreads();
        for (int w = 64; w > 0; w >>= 1) { if (tid < w) red[tid] += red[tid + w]; __syncthreads(); }
        float Z = red[0];
        if (tid < 128) pdb16[(size_t)bt2 * 128 + tid] = (ushort)bf16s((t > 0) ? ex / Z : 0.f);
    }
}

// ---------------- ctxAB: blk<16 ectx = aw @ ench; else dctx = P @ h1d.
__global__ void __launch_bounds__(512) ctxAB(
        const ushort* __restrict__ awb16, const ushort* __restrict__ enchT,
        float* __restrict__ ectx,
        const ushort* __restrict__ pdb16, const ushort* __restrict__ h1dB2,
        float* __restrict__ dctx) {
    __shared__ __align__(16) char smem[32768];
    int blk = blockIdx.x;
    if (blk < 16) {
        int b = blk;
        gemm16_body<16, 32, 512, false>(smem,
            awb16 + ((size_t)(b * 128)) * 512, 512,
            enchT + ((size_t)b << 18),
            ectx + ((size_t)(b * 128)) * 512, 512);
    } else {
        int b = blk - 16;
        gemm16_body<4, 32, 512, false>(smem,
            pdb16 + ((size_t)(b * 128)) * 128, 128,
            h1dB2 + ((size_t)b << 16),
            dctx + ((size_t)(b * 128)) * 512, 512);
    }
}

// ---------------- concat + p_gen; writes bf16 ccb16. grid B*T, 512 thr
__global__ void concat_k(const float* __restrict__ h1d, const float* __restrict__ ectx,
                         const float* __restrict__ dctx, const float* __restrict__ sW,
                         const float* __restrict__ sb, ushort* __restrict__ ccb16,
                         float* __restrict__ pgen) {
    int bt = blockIdx.x;
    int b = bt / T, t = bt - b * T;
    int d = threadIdx.x;
    __shared__ float red[512];
    float v0 = h1d[((size_t)(t * B + b)) * D + d];
    float v1 = ectx[(size_t)bt * D + d];
    float v2 = dctx[(size_t)bt * D + d];
    ushort* c = ccb16 + (size_t)bt * C3;
    c[d] = (ushort)bf16s(v0); c[D + d] = (ushort)bf16s(v1); c[2 * D + d] = (ushort)bf16s(v2);
    red[d] = v0 * sW[d] + v1 * sW[D + d] + v2 * sW[2 * D + d];
    __syncthreads();
    for (int w = 256; w > 0; w >>= 1) { if (d < w) red[d] += red[d + w]; __syncthreads(); }
    if (d == 0) pgen[bt] = 1.f / (1.f + __expf(-(red[0] + sb[0])));
}

// ---------------- vocab GEMM: register-A (M=128), LDS dbuf B stream (passing).
__global__ void __launch_bounds__(512) vocab_mfma3(
        const __hip_bfloat16* __restrict__ outT2, const ushort* __restrict__ ccb16,
        const float* __restrict__ ob, const int* __restrict__ tgt,
        float* __restrict__ pbuf) {
    __shared__ __align__(16) ushort Bs[2][3072 * 8];
    __shared__ int jstar_s[128];
    int bid = blockIdx.x;
    int rb = bid & 15, jg = bid >> 4;
    int row0 = rb * 128;
    int tid = threadIdx.x;
    int lane = tid & 63, w = tid >> 6;
    int cl = lane & 15, hi = lane >> 4;
    int j0base = jg * 2000;

    if (tid < 128) {
        int nt = tgt[row0 + tid];
        int ix = nt - 3;
        ix = ix < 0 ? 0 : (ix > VO - 1 ? VO - 1 : ix);
        jstar_s[tid] = ix;
    }
    short8 a[48];
    {
        const ushort* asrc = ccb16 + (size_t)(row0 + w * 16 + cl) * C3 + hi * 8;
#pragma unroll
        for (int kt = 0; kt < 48; kt++) a[kt] = *(const short8*)(asrc + kt * 32);
    }
    {
#pragma unroll
        for (int ii = 0; ii < 6; ii++) {
            int c = w * 384 + ii * 64 + lane;
            int o = c >> 4, jl = c & 15;
            const char* g = (const char*)outT2 + ((size_t)o * JS + (size_t)(j0base + jl)) * 16;
            gload_lds16(g, (char*)&Bs[0][0] + (size_t)(w * 384 + ii * 64) * 16);
        }
    }
    asm volatile("s_waitcnt vmcnt(0)" ::: "memory");
    __syncthreads();
    int jst[4];
    float m[4], sacc[4], gl[4];
#pragma unroll
    for (int i = 0; i < 4; i++) {
        jst[i] = jstar_s[w * 16 + hi * 4 + i];
        m[i] = -1e30f; sacc[i] = 0.f; gl[i] = -1e30f;
    }
    int buf = 0;
    for (int t = 0; t < 125; t++) {
        if (t + 1 < 125) {
            int j0 = j0base + (t + 1) * 16;
#pragma unroll
            for (int ii = 0; ii < 6; ii++) {
                int c = w * 384 + ii * 64 + lane;
                int o = c >> 4, jl = c & 15;
                const char* g = (const char*)outT2 + ((size_t)o * JS + (size_t)(j0 + jl)) * 16;
                gload_lds16(g, (char*)&Bs[buf ^ 1][0] + (size_t)(w * 384 + ii * 64) * 16);
            }
        }
        f32x4 acc = {0.f, 0.f, 0.f, 0.f};
        const ushort* bp = &Bs[buf][0] + (size_t)(hi * 16 + cl) * 8;
#pragma unroll
        for (int kt = 0; kt < 48; kt++) {
            short8 b = *(const short8*)(bp + (size_t)kt * 512);
            acc = __builtin_amdgcn_mfma_f32_16x16x32_bf16(a[kt], b, acc, 0, 0, 0);
        }
        int j = j0base + t * 16 + cl;
        bool valid = j < VO;
        float obj = valid ? ob[j] : 0.f;
#pragma unroll
        for (int i = 0; i < 4; i++) {
            float L = acc[i] + obj;
            if (valid) {
                if (j == jst[i]) gl[i] = L;
                float mn = fmaxf(m[i], L);
                sacc[i] = sacc[i] * __expf(m[i] - mn) + __expf(L - mn);
                m[i] = mn;
            }
        }
        asm volatile("s_waitcnt vmcnt(0)" ::: "memory");
        __syncthreads();
        buf ^= 1;
    }
#pragma unroll
    for (int i = 0; i < 4; i++) {
        for (int mask = 1; mask < 16; mask <<= 1) {
            float om = __shfl_xor(m[i], mask);
            float os = __shfl_xor(sacc[i], mask);
            float mn = fmaxf(m[i], om);
            sacc[i] = sacc[i] * __expf(m[i] - mn) + os * __expf(om - mn);
            m[i] = mn;
            gl[i] = fmaxf(gl[i], __shfl_xor(gl[i], mask));
        }
    }
    if (cl == 0) {
#pragma unroll
        for (int i = 0; i < 4; i++) {
            int rl = w * 16 + hi * 4 + i;
            float* o = pbuf + ((size_t)(jg * 16 + rb) * 128 + rl) * 4;
            o[0] = m[i]; o[1] = sacc[i]; o[2] = gl[i];
        }
    }
}

// ---------------- combine 16 jg-partials + pointer mix + NLL. grid B, 128 threads.
__global__ void combine_nll_k(const float* __restrict__ pbuf, const int* __restrict__ tgt,
                              const float* __restrict__ pgen, const float* __restrict__ copyp,
                              const int* __restrict__ tlen, float* __restrict__ out) {
    int b = blockIdx.x, t = threadIdx.x;
    int row = b * T + t;
    int rb = row >> 7, rl = row & 127;
    float M = -1e30f, SS = 0.f, GL = -1e30f;
#pragma unroll
    for (int q = 0; q < 16; q++) {
        const float* p = pbuf + ((size_t)(q * 16 + rb) * 128 + rl) * 4;
        float mq = p[0], sq = p[1], gq = p[2];
        float mn = fmaxf(M, mq);
        SS = SS * __expf(M - mn) + sq * __expf(mq - mn);
        M = mn;
        GL = fmaxf(GL, gq);
    }
    int nt = tgt[row];
    float genp = (nt >= 3 && nt < V) ? __expf(GL - M) / SS : 0.f;
    float pg = pgen[row];
    float p = pg * genp + (1.f - pg) * copyp[row];
    __shared__ float red[128];
    red[t] = (t < tlen[b]) ? -logf(p + 1e-9f) : 0.f;
    __syncthreads();
    for (int w = 64; w > 0; w >>= 1) { if (t < w) red[t] += red[t + w]; __syncthreads(); }
    if (t == 0) out[b] = red[0];
}

extern "C" void kernel_launch(void* const* d_in, const int* in_sizes, int n_in,
                              void* d_out, int out_size, void* d_ws, size_t ws_size,
                              hipStream_t stream) {
    const int* input_ids = (const int*)d_in[0];
    const int* target_ids = (const int*)d_in[1];
    const int* tlen = (const int*)d_in[3];
    const float* emb = (const float*)d_in[5];
    const float* eWih0f = (const float*)d_in[6],  *eWhh0f = (const float*)d_in[7],  *eb0f = (const float*)d_in[8];
    const float* eWih0b = (const float*)d_in[9],  *eWhh0b = (const float*)d_in[10], *eb0b = (const float*)d_in[11];
    const float* eWih1f = (const float*)d_in[12], *eWhh1f = (const float*)d_in[13], *eb1f = (const float*)d_in[14];
    const float* eWih1b = (const float*)d_in[15], *eWhh1b = (const float*)d_in[16], *eb1b = (const float*)d_in[17];
    const float* dWih0 = (const float*)d_in[18], *dWhh0 = (const float*)d_in[19], *db0 = (const float*)d_in[20];
    const float* dWih1 = (const float*)d_in[21], *dWhh1 = (const float*)d_in[22], *db1 = (const float*)d_in[23];
    const float* Wenc = (const float*)d_in[24], *Wdec = (const float*)d_in[25];
    const float* Wvoc = (const float*)d_in[26], *sW = (const float*)d_in[27], *sb = (const float*)d_in[28];
    const float* ob = (const float*)d_in[29];
    float* out = (float*)d_out;
    (void)ws_size; (void)n_in; (void)in_sizes; (void)out_size;

    // ============ workspace layout (~193 MB, phase-aliased) ============
    char* A = (char*)d_ws;                          // 98,304,000 B
    float4* pWih0f = (float4*)(A + 0);
    float4* pWih0b = (float4*)(A + 524288);
    ushort* PMW1f  = (ushort*)(A + 1048576);
    ushort* PMW1b  = (ushort*)(A + 2097152);
    float4* pdWih0 = (float4*)(A + 5242880);
    ushort* PMf0  = (ushort*)(A + 6291456);
    ushort* PMb0  = (ushort*)(A + 6815744);
    ushort* PMf1  = (ushort*)(A + 7340032);
    ushort* PMb1  = (ushort*)(A + 7864320);
    float* G0f = (float*)(A + 23068672);
    float* G0b = (float*)(A + 56623104);
    __hip_bfloat16* outT2 = (__hip_bfloat16*)A;     // whole region (megaC)

    char* Bh = A + 98304000;                        // 16,777,216 B
    float* h0f = (float*)(Bh + 0);
    float* h0b = (float*)(Bh + 8388608);
    float* h1d = (float*)(Bh + 0);                  // aliases h0f
    ushort* qeb16 = (ushort*)(Bh + 4194304);        // 2 MB
    ushort* awb16 = (ushort*)(Bh + 6291456);        // 2 MB
    ushort* qdb16 = (ushort*)(Bh + 8388608);        // 2 MB (aliases dead h0b)
    ushort* h1dB1 = (ushort*)(Bh + 10485760);       // 2 MB
    float* ew  = (float*)(Bh + 12582912);           // 4 MB
    float* pbuf = (float*)(Bh + 12582912);          // aliases ew (dead after smAB)

    char* Cr = Bh + 16777216;
    float* h1f = (float*)(Cr + 0);
    float* h1b = (float*)(Cr + 8388608);
    ushort* ccb16 = (ushort*)(Cr + 16777216);       // ends 23068672
    float*  dsout = (float*)(Cr + 23068672);        // 1 MB
    ushort* pdb16 = (ushort*)(Cr + 24117248);       // 0.5 MB
    ushort* h1dB2 = (ushort*)(Cr + 24641536);       // 2 MB
    float* dec_init = (float*)(Cr + 29360128);
    float* pgen  = (float*)(Cr + 29425664);
    float* copyp = (float*)(Cr + 29433856);
    uint* hpkE0  = (uint*)(Cr + 29769728);
    uint* hpkE1  = (uint*)(Cr + 29835264);
    uint* h0pkD  = (uint*)(Cr + 29900800);
    uint* h1pkD  = (uint*)(Cr + 29966336);

    char* X = Cr + 30031872;
    float*  Gd0x  = (float*)(X + 0);                // 16,777,216
    ushort* PM0x  = (ushort*)(X + 16777216);        // 2,097,152
    ushort* PM1x  = (ushort*)(X + 18874368);        // 4,194,304
    ushort* enchB = (ushort*)(X + 23068672);        // 8,388,608
    float*  ectx  = (float*)(X + 31457280);         // 4,194,304
    float*  dctx  = (float*)(X + 35651584);         // 4,194,304
    ushort* enchT = (ushort*)(X + 39845888);        // 8,388,608
    // total ≈ 193,347,584 B

    hipMemsetAsync(hpkE0, 0, 262144, stream);

    auto pack = [&](const float* W, float4* P, int Hn, int K) {
        int total = Hn * K;
        hipLaunchKernelGGL(pack4_kernel, dim3((total + 255) / 256), dim3(256), 0, stream, W, P, Hn, K);
    };
    pack(eWih0f, pWih0f, H, E);
    pack(eWih0b, pWih0b, H, E);
    pack(dWih0, pdWih0, D, E);
    hipLaunchKernelGGL(packencMK_k, dim3(4 * H * 256 / 256), dim3(256), 0, stream, eWhh0f, PMf0, 256);
    hipLaunchKernelGGL(packencMK_k, dim3(4 * H * 256 / 256), dim3(256), 0, stream, eWhh0b, PMb0, 256);
    hipLaunchKernelGGL(packencMK_k, dim3(4 * H * 256 / 256), dim3(256), 0, stream, eWhh1f, PMf1, 256);
    hipLaunchKernelGGL(packencMK_k, dim3(4 * H * 256 / 256), dim3(256), 0, stream, eWhh1b, PMb1, 256);
    hipLaunchKernelGGL(packencMK_k, dim3(4 * H * 512 / 256), dim3(256), 0, stream, eWih1f, PMW1f, 512);
    hipLaunchKernelGGL(packencMK_k, dim3(4 * H * 512 / 256), dim3(256), 0, stream, eWih1b, PMW1b, 512);
    hipLaunchKernelGGL(packdecM_k, dim3(4 * D * D / 256), dim3(256), 0, stream, dWhh0, PM0x);
    hipLaunchKernelGGL(packdecM2_k, dim3(8 * D * D / 256), dim3(256), 0, stream, dWih1, dWhh1, PM1x);

    hipLaunchKernelGGL(enc0_gates2, dim3(S * B / 8), dim3(256), 0, stream,
                       input_ids, emb, pWih0f, eb0f, pWih0b, eb0b, G0f, G0b);
    hipLaunchKernelGGL(megaA, dim3(272), dim3(256), 0, stream,
                       G0f, G0b, PMf0, PMb0, h0f, h0b, dec_init, hpkE0,
                       target_ids, emb, pdWih0, db0, Gd0x);
    hipLaunchKernelGGL(enc1g_mfma, dim3(256), dim3(256), 0, stream,
                       h0f, h0b, PMW1f, PMW1b, eb1f, eb1b, G0f, G0b);
    hipLaunchKernelGGL(enc_pscan3, dim3(16), dim3(256), 0, stream,
                       G0f, G0b, PMf1, PMb1, h1f, h1b, dec_init + B * D, hpkE1);
    hipLaunchKernelGGL(dec_initpk, dim3(B * D / 256), dim3(256), 0, stream,
                       dec_init, h0pkD, h1pkD);
    hipLaunchKernelGGL(megaC, dim3(5128), dim3(256), 0, stream,
                       Gd0x, PM0x, PM1x, db1, h0pkD, h1pkD, h1d,
                       h1f, h1b, enchB, enchT, emb, Wvoc, outT2);
    hipLaunchKernelGGL(qproj, dim3(T * B), dim3(D), 0, stream,
                       h1d, Wenc, Wdec, qeb16, qdb16, h1dB1);
    hipLaunchKernelGGL(pack_h1dB2, dim3(512), dim3(256), 0, stream, h1d, h1dB2);
    hipLaunchKernelGGL(scoreAB, dim3(32), dim3(512), 0, stream,
                       qeb16, enchB, ew, qdb16, h1dB1, dsout);
    hipLaunchKernelGGL(temporal_k, dim3((B * S + 255) / 256), dim3(256), 0, stream, ew);
    hipLaunchKernelGGL(smAB, dim3(4096), dim3(512), 0, stream,
                       ew, input_ids, target_ids, awb16, copyp, dsout, pdb16);
    hipLaunchKernelGGL(ctxAB, dim3(32), dim3(512), 0, stream,
                       awb16, enchT, ectx, pdb16, h1dB2, dctx);
    hipLaunchKernelGGL(concat_k, dim3(B * T), dim3(D), 0, stream,
                       h1d, ectx, dctx, sW, sb, ccb16, pgen);
    hipLaunchKernelGGL(vocab_mfma3, dim3(256), dim3(512), 0, stream,
                       outT2, ccb16, ob, target_ids, pbuf);
    hipLaunchKernelGGL(combine_nll_k, dim3(B), dim3(T), 0, stream,
                       pbuf, target_ids, pgen, copyp, tlen, out);
}

// Round 17
// 4002.312 us; speedup vs baseline: 5.7491x; 1.0002x over previous
//
#include <hip/hip_runtime.h>
#include <hip/hip_bf16.h>
#include <math.h>

#define PAD_ID 0
#define UNK_ID 1
#define START_ID 2
#define END_ID 3

constexpr int B = 16, S = 512, T = 128, V = 32000, E = 128, H = 256, D = 512;
constexpr int C3 = 1536;        // 3*D
constexpr int VO = 31997;       // V-3
constexpr int JS = 32000;       // padded col count for outT2

typedef short short8 __attribute__((ext_vector_type(8)));
typedef float f32x4 __attribute__((ext_vector_type(4)));

__device__ __forceinline__ float sigm(float x) { return 1.0f / (1.0f + __expf(-x)); }
__device__ __forceinline__ short bf16s(float x) {
    __hip_bfloat16 h = __float2bfloat16(x);
    return *reinterpret_cast<short*>(&h);
}

__device__ __forceinline__ uint4 cloadu4(const uint* p) {
    uint4 v;
    asm volatile("global_load_dwordx4 %0, %1, off sc0 sc1" : "=v"(v) : "v"(p));
    return v;
}
__device__ __forceinline__ void pstore(uint* p, uint v) {
    __hip_atomic_store(p, v, __ATOMIC_RELAXED, __HIP_MEMORY_SCOPE_AGENT);
}

__device__ __forceinline__ void gload_lds16(const void* g, void* l) {
    __builtin_amdgcn_global_load_lds(
        (const __attribute__((address_space(1))) void*)(g),
        (__attribute__((address_space(3))) void*)(l), 16, 0, 0);
}

__device__ __forceinline__ void st_bf8(ushort* dst, float4 a, float4 b) {
    short8 o;
    o[0] = bf16s(a.x); o[1] = bf16s(a.y); o[2] = bf16s(a.z); o[3] = bf16s(a.w);
    o[4] = bf16s(b.x); o[5] = bf16s(b.y); o[6] = bf16s(b.z); o[7] = bf16s(b.w);
    *(short8*)dst = o;
}

// ---------------- poll 16 packets tagged e; write 16 bf16 to dst
__device__ __forceinline__ void poll_stage16(const uint* src, uint e, ushort* dst) {
    uint4 a0, a1, a2, a3;
    for (;;) {
        a0 = cloadu4(src); a1 = cloadu4(src + 4); a2 = cloadu4(src + 8); a3 = cloadu4(src + 12);
        asm volatile("s_waitcnt vmcnt(0)" ::: "memory");
        __builtin_amdgcn_sched_barrier(0);
        uint d = (a0.x ^ e) | (a0.y ^ e) | (a0.z ^ e) | (a0.w ^ e)
               | (a1.x ^ e) | (a1.y ^ e) | (a1.z ^ e) | (a1.w ^ e)
               | (a2.x ^ e) | (a2.y ^ e) | (a2.z ^ e) | (a2.w ^ e)
               | (a3.x ^ e) | (a3.y ^ e) | (a3.z ^ e) | (a3.w ^ e);
        if ((d & 0xffffu) == 0) break;
        __builtin_amdgcn_s_sleep(1);
    }
    short8 o0, o1;
    o0[0] = (short)(a0.x >> 16); o0[1] = (short)(a0.y >> 16); o0[2] = (short)(a0.z >> 16); o0[3] = (short)(a0.w >> 16);
    o0[4] = (short)(a1.x >> 16); o0[5] = (short)(a1.y >> 16); o0[6] = (short)(a1.z >> 16); o0[7] = (short)(a1.w >> 16);
    o1[0] = (short)(a2.x >> 16); o1[1] = (short)(a2.y >> 16); o1[2] = (short)(a2.z >> 16); o1[3] = (short)(a2.w >> 16);
    o1[4] = (short)(a3.x >> 16); o1[5] = (short)(a3.y >> 16); o1[6] = (short)(a3.z >> 16); o1[7] = (short)(a3.w >> 16);
    *(short8*)dst = o0;
    *(short8*)(dst + 8) = o1;
}

// ---------------- fused poll of TWO 32-packet regions tagged e; one wait loop.
__device__ __forceinline__ void poll_stage32x2(const uint* s0, const uint* s1, uint e,
                                               ushort* d0, ushort* d1) {
    uint4 a[16];
    for (;;) {
#pragma unroll
        for (int i = 0; i < 8; i++) a[i] = cloadu4(s0 + i * 4);
#pragma unroll
        for (int i = 0; i < 8; i++) a[8 + i] = cloadu4(s1 + i * 4);
        asm volatile("s_waitcnt vmcnt(0)" ::: "memory");
        __builtin_amdgcn_sched_barrier(0);
        uint d = 0;
#pragma unroll
        for (int i = 0; i < 16; i++)
            d |= (a[i].x ^ e) | (a[i].y ^ e) | (a[i].z ^ e) | (a[i].w ^ e);
        if ((d & 0xffffu) == 0) break;
        __builtin_amdgcn_s_sleep(1);
    }
#pragma unroll
    for (int i = 0; i < 8; i += 2) {
        short8 o;
        o[0] = (short)(a[i].x >> 16);     o[1] = (short)(a[i].y >> 16);
        o[2] = (short)(a[i].z >> 16);     o[3] = (short)(a[i].w >> 16);
        o[4] = (short)(a[i + 1].x >> 16); o[5] = (short)(a[i + 1].y >> 16);
        o[6] = (short)(a[i + 1].z >> 16); o[7] = (short)(a[i + 1].w >> 16);
        *(short8*)(d0 + i * 4) = o;
    }
#pragma unroll
    for (int i = 0; i < 8; i += 2) {
        short8 o;
        o[0] = (short)(a[8 + i].x >> 16);     o[1] = (short)(a[8 + i].y >> 16);
        o[2] = (short)(a[8 + i].z >> 16);     o[3] = (short)(a[8 + i].w >> 16);
        o[4] = (short)(a[8 + i + 1].x >> 16); o[5] = (short)(a[8 + i + 1].y >> 16);
        o[6] = (short)(a[8 + i + 1].z >> 16); o[7] = (short)(a[8 + i + 1].w >> 16);
        *(short8*)(d1 + i * 4) = o;
    }
}

// ---------------- weight packing: W[4H][K] -> P[k][u] = float4 of 4 gates
__global__ void pack4_kernel(const float* __restrict__ W, float4* __restrict__ P, int Hn, int K) {
    int i = blockIdx.x * blockDim.x + threadIdx.x;
    if (i >= K * Hn) return;
    int k = i / Hn, u = i - k * Hn;
    float4 v;
    v.x = W[(size_t)(0 * Hn + u) * K + k];
    v.y = W[(size_t)(1 * Hn + u) * K + k];
    v.z = W[(size_t)(2 * Hn + u) * K + k];
    v.w = W[(size_t)(3 * Hn + u) * K + k];
    P[(size_t)k * Hn + u] = v;
}

// ---------------- MFMA-row pack (H=256 outputs): row = (u>>3)*32 + g*8 + (u&7)
__global__ void packencMK_k(const float* __restrict__ W, ushort* __restrict__ P, int K) {
    int i = blockIdx.x * blockDim.x + threadIdx.x;
    if (i >= 4 * H * K) return;
    int k = i % K, row = i / K;
    int g = (row >> 3) & 3, ul = row & 7, uh = row >> 5;
    int u = uh * 8 + ul;
    P[i] = (ushort)bf16s(W[(size_t)(g * H + u) * K + k]);
}

// ---------------- decoder W0 pack for MFMA (row = bk*64 + g*16 + u%16)
__global__ void packdecM_k(const float* __restrict__ W, ushort* __restrict__ P) {
    int i = blockIdx.x * blockDim.x + threadIdx.x;
    if (i >= 4 * D * D) return;
    int k = i & 511, row = i >> 9;
    int g = (row >> 4) & 3, u = (row >> 6) * 16 + (row & 15);
    P[i] = (ushort)bf16s(W[(size_t)(g * D + u) * D + k]);
}

// ---------------- decoder layer1 pack: [W1i | W1h] -> PM1[row][1024] bf16
__global__ void packdecM2_k(const float* __restrict__ Wi, const float* __restrict__ Wh,
                            ushort* __restrict__ P) {
    int i = blockIdx.x * blockDim.x + threadIdx.x;
    if (i >= 4 * D * D * 2) return;
    int k = i & 1023, row = i >> 10;
    int g = (row >> 4) & 3, u = (row >> 6) * 16 + (row & 15);
    float v = (k < 512) ? Wi[(size_t)(g * D + u) * D + k]
                        : Wh[(size_t)(g * D + u) * D + (k - 512)];
    P[i] = (ushort)bf16s(v);
}

// ---------------- encoder layer-0 gates, tiled (8 rows/block). grid S*B/8, 256 thr.
__global__ void enc0_gates2(const int* __restrict__ ids, const float* __restrict__ emb,
                            const float4* __restrict__ Pf, const float* __restrict__ bf_,
                            const float4* __restrict__ Pb, const float* __restrict__ bb_,
                            float* __restrict__ Gf, float* __restrict__ Gb) {
    int n0 = blockIdx.x * 8;
    int u = threadIdx.x;
    __shared__ float xr[8][E];
    for (int i = u; i < 8 * E; i += 256) {
        int r = i >> 7, e = i & 127;
        int n = n0 + r, s = n / B, b = n - s * B;
        int tok = ids[b * S + s];
        if (tok >= V) tok = UNK_ID;
        xr[r][e] = emb[(size_t)tok * E + e];
    }
    __syncthreads();
#pragma unroll
    for (int dir = 0; dir < 2; dir++) {
        const float4* P = dir ? Pb : Pf;
        const float* bs = dir ? bb_ : bf_;
        float* G = dir ? Gb : Gf;
        float acc[8][4];
#pragma unroll
        for (int r = 0; r < 8; r++)
#pragma unroll
            for (int g = 0; g < 4; g++) acc[r][g] = 0.f;
#pragma unroll 4
        for (int k = 0; k < E; k++) {
            float4 w = P[k * H + u];
#pragma unroll
            for (int r = 0; r < 8; r++) {
                float x = xr[r][k];
                acc[r][0] += x * w.x; acc[r][1] += x * w.y;
                acc[r][2] += x * w.z; acc[r][3] += x * w.w;
            }
        }
        float b0 = bs[u], b1 = bs[H + u], b2 = bs[2 * H + u], b3 = bs[3 * H + u];
#pragma unroll
        for (int r = 0; r < 8; r++) {
            float* g = G + (size_t)(n0 + r) * (4 * H);
            g[u] = acc[r][0] + b0; g[H + u] = acc[r][1] + b1;
            g[2 * H + u] = acc[r][2] + b2; g[3 * H + u] = acc[r][3] + b3;
        }
    }
}

// ---------------- encoder layer-1 gates via MFMA. grid 256, 256 thr.
__global__ void __launch_bounds__(256) enc1g_mfma(
        const float* __restrict__ h0f, const float* __restrict__ h0b,
        const ushort* __restrict__ PMf, const ushort* __restrict__ PMb,
        const float* __restrict__ bf_, const float* __restrict__ bb_,
        float* __restrict__ Gf, float* __restrict__ Gb) {
    __shared__ __align__(16) ushort X[16 * 520];
    __shared__ float gs[4][32][17];
    __shared__ float bias_s[128];
    int bid = blockIdx.x;
    int dirb = (bid >> 3) & 1, bk = bid & 7, ns = bid >> 4;
    const ushort* PM = dirb ? PMb : PMf;
    const float* bs = dirb ? bb_ : bf_;
    float* G = dirb ? Gb : Gf;
    int tid = threadIdx.x;
    int lane = tid & 63, w = tid >> 6;
    int cl = lane & 15, hi = lane >> 4;

    short8 afr[2][16];
    {
        int rowbase = (bk * 4 + w) * 32;
#pragma unroll
        for (int mt = 0; mt < 2; mt++)
#pragma unroll
            for (int kt = 0; kt < 16; kt++)
                afr[mt][kt] = *(const short8*)(PM + (size_t)(rowbase + mt * 16 + cl) * 512 + kt * 32 + hi * 8);
    }
    if (tid < 128) {
        int g = (tid >> 3) & 3;
        int u = (bk * 4 + (tid >> 5)) * 8 + (tid & 7);
        bias_s[tid] = bs[g * H + u];
    }
    int nl = tid >> 4, kseg = tid & 15;
    int en = tid & 15, rgrp = tid >> 4;
    for (int tt = 0; tt < 32; tt++) {
        int nt = ns * 32 + tt;
        __syncthreads();
        {
            int n = nt * 16 + nl;
            const float* src = (kseg < 8) ? (h0f + (size_t)n * H + kseg * 32)
                                          : (h0b + (size_t)n * H + (kseg - 8) * 32);
            float4 v0 = *(const float4*)(src), v1 = *(const float4*)(src + 4);
            float4 v2 = *(const float4*)(src + 8), v3 = *(const float4*)(src + 12);
            float4 v4 = *(const float4*)(src + 16), v5 = *(const float4*)(src + 20);
            float4 v6 = *(const float4*)(src + 24), v7 = *(const float4*)(src + 28);
            ushort* dst = X + nl * 520 + kseg * 32;
            st_bf8(dst, v0, v1); st_bf8(dst + 8, v2, v3);
            st_bf8(dst + 16, v4, v5); st_bf8(dst + 24, v6, v7);
        }
        __syncthreads();
        {
            f32x4 acc0 = {0.f, 0.f, 0.f, 0.f}, acc1 = {0.f, 0.f, 0.f, 0.f};
            const ushort* hp = X + cl * 520 + hi * 8;
#pragma unroll
            for (int kt = 0; kt < 16; kt++) {
                short8 bfr = *(const short8*)(hp + kt * 32);
                acc0 = __builtin_amdgcn_mfma_f32_16x16x32_bf16(afr[0][kt], bfr, acc0, 0, 0, 0);
                acc1 = __builtin_amdgcn_mfma_f32_16x16x32_bf16(afr[1][kt], bfr, acc1, 0, 0, 0);
            }
#pragma unroll
            for (int i = 0; i < 4; i++) {
                gs[w][hi * 4 + i][cl] = acc0[i];
                gs[w][16 + hi * 4 + i][cl] = acc1[i];
            }
        }
        __syncthreads();
        {
            int wv = rgrp >> 2, g = rgrp & 3;
            int u0 = (bk * 4 + wv) * 8;
            float* dst = G + (size_t)(nt * 16 + en) * 1024 + g * 256 + u0;
            float4 o0, o1;
            o0.x = gs[wv][g * 8 + 0][en] + bias_s[rgrp * 8 + 0];
            o0.y = gs[wv][g * 8 + 1][en] + bias_s[rgrp * 8 + 1];
            o0.z = gs[wv][g * 8 + 2][en] + bias_s[rgrp * 8 + 2];
            o0.w = gs[wv][g * 8 + 3][en] + bias_s[rgrp * 8 + 3];
            o1.x = gs[wv][g * 8 + 4][en] + bias_s[rgrp * 8 + 4];
            o1.y = gs[wv][g * 8 + 5][en] + bias_s[rgrp * 8 + 5];
            o1.z = gs[wv][g * 8 + 6][en] + bias_s[rgrp * 8 + 6];
            o1.w = gs[wv][g * 8 + 7][en] + bias_s[rgrp * 8 + 7];
            *(float4*)dst = o0;
            *(float4*)(dst + 4) = o1;
        }
    }
}

// ================= device bodies =================

// ---- enc scan body (dataflow packets). blk in [0,16).
__device__ __forceinline__ void enc_scan_body(int blk, char* smem,
        const float* __restrict__ Gf, const float* __restrict__ Gb,
        const ushort* __restrict__ PMf, const ushort* __restrict__ PMb,
        float* __restrict__ hof, float* __restrict__ hob,
        float* __restrict__ hfin, uint* __restrict__ pk) {
    ushort* hh = (ushort*)smem;
    float (*gs)[32][17] = (float(*)[32][17])(smem + 8448);
    int dirb = blk >> 3, bk = blk & 7;
    const float* G = dirb ? Gb : Gf;
    const ushort* PM = dirb ? PMb : PMf;
    float* ho = dirb ? hob : hof;
    int tid = threadIdx.x;
    int lane = tid & 63, w = tid >> 6;
    int cl = lane & 15, hi = lane >> 4;

    short8 afr[2][8];
    {
        int rowbase = (bk * 4 + w) * 32;
#pragma unroll
        for (int mt = 0; mt < 2; mt++)
#pragma unroll
            for (int kt = 0; kt < 8; kt++)
                afr[mt][kt] = *(const short8*)(PM + (size_t)(rowbase + mt * 16 + cl) * 256 + kt * 32 + hi * 8);
    }
    int ub = tid & 31, bb = tid >> 5;
    int u_glob = bk * 32 + ub;
    int gsw = ub >> 3, ul = ub & 7;
    float c_a = 0.f, c_b = 0.f;
    int b0s = tid >> 4, u0s = (tid & 15) * 16;

    for (int step = 0; step < S; step++) {
        int s = dirb ? (S - 1 - step) : step;
        int cur = step & 1;
        const float* gA = G + ((size_t)(s * B + bb)) * 1024 + u_glob;
        const float* gB = G + ((size_t)(s * B + bb + 8)) * 1024 + u_glob;
        float pa0 = gA[0], pa1 = gA[256], pa2 = gA[512], pa3 = gA[768];
        float pb0 = gB[0], pb1 = gB[256], pb2 = gB[512], pb3 = gB[768];
        poll_stage16(pk + cur * 8192 + dirb * 4096 + tid * 16,
                     (uint)step & 0xffffu, hh + b0s * 264 + u0s);
        __syncthreads();
        {
            f32x4 acc0 = {0.f, 0.f, 0.f, 0.f}, acc1 = {0.f, 0.f, 0.f, 0.f};
            const ushort* hp = hh + cl * 264 + hi * 8;
#pragma unroll
            for (int kt = 0; kt < 8; kt++) {
                short8 bfr = *(const short8*)(hp + kt * 32);
                acc0 = __builtin_amdgcn_mfma_f32_16x16x32_bf16(afr[0][kt], bfr, acc0, 0, 0, 0);
                acc1 = __builtin_amdgcn_mfma_f32_16x16x32_bf16(afr[1][kt], bfr, acc1, 0, 0, 0);
            }
#pragma unroll
            for (int i = 0; i < 4; i++) {
                gs[w][hi * 4 + i][cl] = acc0[i];
                gs[w][16 + hi * 4 + i][cl] = acc1[i];
            }
        }
        __syncthreads();
        {
            float q0 = gs[gsw][0 + ul][bb];
            float q1 = gs[gsw][8 + ul][bb];
            float q2 = gs[gsw][16 + ul][bb];
            float q3 = gs[gsw][24 + ul][bb];
            float ig = sigm(pa0 + q0), fg = sigm(pa1 + q1), gt = tanhf(pa2 + q2), og = sigm(pa3 + q3);
            c_a = fg * c_a + ig * gt;
            float hA = og * tanhf(c_a);
            q0 = gs[gsw][0 + ul][bb + 8];
            q1 = gs[gsw][8 + ul][bb + 8];
            q2 = gs[gsw][16 + ul][bb + 8];
            q3 = gs[gsw][24 + ul][bb + 8];
            ig = sigm(pb0 + q0); fg = sigm(pb1 + q1); gt = tanhf(pb2 + q2); og = sigm(pb3 + q3);
            c_b = fg * c_b + ig * gt;
            float hB = og * tanhf(c_b);
            uint tg = (uint)(step + 1) & 0xffffu;
            uint* dstp = pk + (cur ^ 1) * 8192 + dirb * 4096;
            pstore(&dstp[bb * 256 + u_glob], ((uint)(ushort)bf16s(hA) << 16) | tg);
            pstore(&dstp[(bb + 8) * 256 + u_glob], ((uint)(ushort)bf16s(hB) << 16) | tg);
            ho[((size_t)(s * B + bb)) * H + u_glob] = hA;
            ho[((size_t)(s * B + bb + 8)) * H + u_glob] = hB;
            if (step == S - 1) {
                hfin[bb * (2 * H) + dirb * H + u_glob] = hA;
                hfin[(bb + 8) * (2 * H) + dirb * H + u_glob] = hB;
            }
        }
    }
}

// ---- dec0 gates body
__device__ __forceinline__ void dec0_body(int bid, char* smem,
        const int* __restrict__ tgt, const float* __restrict__ emb,
        const float4* __restrict__ P, const float* __restrict__ bias,
        float* __restrict__ G) {
    float (*xr)[E] = (float(*)[E])smem;
    int n0 = bid * 8;
    int tid = threadIdx.x;
    for (int i = tid; i < 8 * E; i += 256) {
        int r = i >> 7, e = i & 127;
        int n = n0 + r, t = n / B, b = n - t * B;
        int tok;
        if (t == 0) tok = START_ID;
        else { tok = tgt[b * T + (t - 1)]; if (tok >= V) tok = UNK_ID; }
        xr[r][e] = emb[(size_t)tok * E + e];
    }
    __syncthreads();
#pragma unroll
    for (int half = 0; half < 2; half++) {
        int u = tid + half * 256;
        float acc[8][4];
#pragma unroll
        for (int r = 0; r < 8; r++)
#pragma unroll
            for (int g = 0; g < 4; g++) acc[r][g] = 0.f;
#pragma unroll 4
        for (int k = 0; k < E; k++) {
            float4 w = P[k * D + u];
#pragma unroll
            for (int r = 0; r < 8; r++) {
                float x = xr[r][k];
                acc[r][0] += x * w.x; acc[r][1] += x * w.y;
                acc[r][2] += x * w.z; acc[r][3] += x * w.w;
            }
        }
        float b0 = bias[u], b1 = bias[D + u], b2 = bias[2 * D + u], b3 = bias[3 * D + u];
#pragma unroll
        for (int r = 0; r < 8; r++) {
            float* g = G + (size_t)(n0 + r) * (4 * D);
            g[u] = acc[r][0] + b0; g[D + u] = acc[r][1] + b1;
            g[2 * D + u] = acc[r][2] + b2; g[3 * D + u] = acc[r][3] + b3;
        }
    }
}

// ---- dec scan body, COMBINED ROUND (R17): one poll+publish per step.
// Round r: inputs h0[r] (tag r+1), h1[r-1] (tag r+1); outputs h0[r+1], h1[r] (tag r+2).
__device__ __forceinline__ void dec_body(int bk, char* smem,
        const float* __restrict__ G0, const ushort* __restrict__ PM0,
        const ushort* __restrict__ PM1, const float* __restrict__ b1,
        uint* __restrict__ h0pk, uint* __restrict__ h1pk,
        const float* __restrict__ c0a, float* __restrict__ h1out) {
    ushort* hb = (ushort*)smem;                              // 33024 B
    float (*gs0)[16][17] = (float(*)[16][17])(smem + 33024); // 4352 B
    float (*gs1)[16][17] = (float(*)[16][17])(smem + 37376); // 4352 B
    int tid = threadIdx.x;
    int lane = tid & 63, w = tid >> 6;
    int cl = lane & 15, hi = lane >> 4;

    short8 a0[16], a1[32];
    {
        const ushort* base0 = PM0 + (size_t)(bk * 64 + w * 16 + cl) * 512 + hi * 8;
#pragma unroll
        for (int kt = 0; kt < 16; kt++) a0[kt] = *(const short8*)(base0 + kt * 32);
        const ushort* base1 = PM1 + (size_t)(bk * 64 + w * 16 + cl) * 1024 + hi * 8;
#pragma unroll
        for (int kt = 0; kt < 32; kt++) a1[kt] = *(const short8*)(base1 + kt * 32);
    }
    int u_loc = tid & 15, b = tid >> 4;
    int u = bk * 16 + u_loc;
    float bi0 = b1[u], bi1 = b1[512 + u], bi2 = b1[1024 + u], bi3 = b1[1536 + u];
    float c0v = c0a[b * 512 + u];      // cell state after step 0 (h0[0] precomputed)
    float c1v = 0.f;
    int sb = tid >> 4, kseg = tid & 15;
    int sflat = sb * 512 + kseg * 32;

    for (int r = 0; r < T; r++) {
        // G0 prefetch for layer-0 output step r+1 (clamped; unused at r==T-1)
        int tn = (r + 1 < T) ? (r + 1) : (T - 1);
        const float* gg = G0 + ((size_t)(tn * B + b)) * 2048 + u;
        float p0 = gg[0], p1 = gg[512], p2 = gg[1024], p3 = gg[1536];
        poll_stage32x2(h0pk + ((r + 1) & 1) * 8192 + sflat,
                       h1pk + ((r + 1) & 1) * 8192 + sflat,
                       (uint)(r + 1) & 0xffffu,
                       hb + sb * 1032 + kseg * 32,
                       hb + sb * 1032 + 512 + kseg * 32);
        __syncthreads();
        {
            f32x4 acc1 = {0.f, 0.f, 0.f, 0.f};
            f32x4 acc0 = {0.f, 0.f, 0.f, 0.f};
            const ushort* hp = hb + cl * 1032 + hi * 8;
#pragma unroll
            for (int kt = 0; kt < 32; kt++) {
                short8 bfr = *(const short8*)(hp + kt * 32);
                acc1 = __builtin_amdgcn_mfma_f32_16x16x32_bf16(a1[kt], bfr, acc1, 0, 0, 0);
                if (kt < 16)
                    acc0 = __builtin_amdgcn_mfma_f32_16x16x32_bf16(a0[kt], bfr, acc0, 0, 0, 0);
            }
#pragma unroll
            for (int i = 0; i < 4; i++) {
                gs1[w][hi * 4 + i][cl] = acc1[i];
                gs0[w][hi * 4 + i][cl] = acc0[i];
            }
        }
        __syncthreads();
        {
            uint tg = (uint)(r + 2) & 0xffffu;
            int pp = r & 1;
            // layer-1: h1[r]
            float g0 = bi0 + gs1[0][u_loc][b];
            float g1 = bi1 + gs1[1][u_loc][b];
            float g2 = bi2 + gs1[2][u_loc][b];
            float g3 = bi3 + gs1[3][u_loc][b];
            float ig = sigm(g0), fg = sigm(g1), gt = tanhf(g2), og = sigm(g3);
            c1v = fg * c1v + ig * gt;
            float h1n = og * tanhf(c1v);
            pstore(&h1pk[pp * 8192 + b * 512 + u],
                   ((uint)(ushort)bf16s(h1n) << 16) | tg);
            h1out[((size_t)(r * B + b)) * 512 + u] = h1n;
            // layer-0: h0[r+1] (skip at final round)
            if (r + 1 < T) {
                g0 = p0 + gs0[0][u_loc][b];
                g1 = p1 + gs0[1][u_loc][b];
                g2 = p2 + gs0[2][u_loc][b];
                g3 = p3 + gs0[3][u_loc][b];
                ig = sigm(g0); fg = sigm(g1); gt = tanhf(g2); og = sigm(g3);
                c0v = fg * c0v + ig * gt;
                float h0n = og * tanhf(c0v);
                pstore(&h0pk[pp * 8192 + b * 512 + u],
                       ((uint)(ushort)bf16s(h0n) << 16) | tg);
            }
        }
        __syncthreads();   // protect hb reuse by next round staging
    }
}

// ---- enchB pack: [b][o(d/8)=64][s(512)][8d]
__device__ __forceinline__ void encht2_body(int bid,
        const float* __restrict__ h1f, const float* __restrict__ h1b,
        ushort* __restrict__ enchB) {
    int idx = bid * 256 + threadIdx.x;
    int b = idx >> 15;
    int r = idx & 32767;
    int o = r >> 9, s = r & 511;
    const float* src = (o < 32) ? (h1f + ((size_t)(s * B + b)) * H + o * 8)
                                : (h1b + ((size_t)(s * B + b)) * H + (o - 32) * 8);
    float4 v0 = *(const float4*)src, v1 = *(const float4*)(src + 4);
    st_bf8(enchB + ((size_t)b << 18) + o * 4096 + s * 8, v0, v1);
}

// ---- enchT pack: [b][o(s/8)=64][d(512)][8s]
__device__ __forceinline__ void encht2T_body(int bid,
        const float* __restrict__ h1f, const float* __restrict__ h1b,
        ushort* __restrict__ enchT) {
    int idx = bid * 256 + threadIdx.x;
    int b = idx >> 15;
    int r = idx & 32767;
    int o = r >> 9, d = r & 511;
    float f[8];
#pragma unroll
    for (int j = 0; j < 8; j++) {
        int s = o * 8 + j;
        f[j] = (d < H) ? h1f[((size_t)(s * B + b)) * H + d]
                       : h1b[((size_t)(s * B + b)) * H + (d - H)];
    }
    float4 v0 = {f[0], f[1], f[2], f[3]}, v1 = {f[4], f[5], f[6], f[7]};
    st_bf8(enchT + ((size_t)b << 18) + o * 4096 + d * 8, v0, v1);
}

// ---- out_proj body
__device__ __forceinline__ void outproj_body(int bid, char* smem,
        const float* __restrict__ emb, const float* __restrict__ Wvoc,
        __hip_bfloat16* __restrict__ outT2) {
    float (*er)[E + 1] = (float(*)[E + 1])smem;
    int j0 = bid * 32;
    int jl = threadIdx.x & 31, oq = threadIdx.x >> 5;
    for (int i = threadIdx.x; i < 32 * E; i += 256) {
        int jj = i >> 7, e = i & 127;
        int j = j0 + jj;
        er[jj][e] = (j < VO) ? emb[(size_t)(3 + j) * E + e] : 0.f;
    }
    __syncthreads();
    int j = j0 + jl;
#pragma unroll 1
    for (int i = 0; i < 24; i++) {
        int o = oq * 24 + i;
        int k0 = o * 8;
        float acc[8];
#pragma unroll
        for (int kk = 0; kk < 8; kk++) acc[kk] = 0.f;
#pragma unroll 4
        for (int e = 0; e < E; e++) {
            float x = er[jl][e];
            float4 w0 = *(const float4*)(Wvoc + (size_t)e * C3 + k0);
            float4 w1 = *(const float4*)(Wvoc + (size_t)e * C3 + k0 + 4);
            acc[0] += x * w0.x; acc[1] += x * w0.y; acc[2] += x * w0.z; acc[3] += x * w0.w;
            acc[4] += x * w1.x; acc[5] += x * w1.y; acc[6] += x * w1.z; acc[7] += x * w1.w;
        }
        short8 v;
#pragma unroll
        for (int kk = 0; kk < 8; kk++) v[kk] = bf16s(tanhf(acc[kk]));
        *reinterpret_cast<short8*>((char*)outT2 + ((size_t)o * JS + j) * 16) = v;
    }
}

// ---- generic MFMA "A-in-regs @ streamed B" body (wave-uniform LDS staging).
template<int NF, int TILES, int OSTR, bool DOEXP>
__device__ __forceinline__ void gemm16_body(char* smem,
        const ushort* __restrict__ Abase, int arow_stride,
        const ushort* __restrict__ Bsrc, float* __restrict__ outbase,
        int out_stride) {
    ushort* Bs = (ushort*)smem;
    const int CH = NF * 64;
    const int NG = CH / 64;
    int tid = threadIdx.x;
    int lane = tid & 63, w = tid >> 6;
    int cl = lane & 15, hi = lane >> 4;
    short8 a[NF];
    {
        const ushort* asrc = Abase + (size_t)(w * 16 + cl) * arow_stride + hi * 8;
#pragma unroll
        for (int kt = 0; kt < NF; kt++) a[kt] = *(const short8*)(asrc + kt * 32);
    }
    for (int g = w; g < NG; g += 8) {
        int c = g * 64 + lane;
        int o = c >> 4, jl = c & 15;
        gload_lds16(Bsrc + ((size_t)o * OSTR + jl) * 8,
                    (char*)Bs + (size_t)(g * 64) * 16);
    }
    asm volatile("s_waitcnt vmcnt(0)" ::: "memory");
    __syncthreads();
    int buf = 0;
    for (int t = 0; t < TILES; t++) {
        if (t + 1 < TILES) {
            for (int g = w; g < NG; g += 8) {
                int c = g * 64 + lane;
                int o = c >> 4, jl = c & 15;
                gload_lds16(Bsrc + ((size_t)o * OSTR + (t + 1) * 16 + jl) * 8,
                            (char*)Bs + (size_t)((buf ^ 1) * CH + g * 64) * 16);
            }
        }
        f32x4 acc = {0.f, 0.f, 0.f, 0.f};
        const ushort* bp = Bs + (size_t)buf * CH * 8 + (size_t)(hi * 16 + cl) * 8;
#pragma unroll
        for (int kt = 0; kt < NF; kt++) {
            short8 b = *(const short8*)(bp + (size_t)kt * 512);
            acc = __builtin_amdgcn_mfma_f32_16x16x32_bf16(a[kt], b, acc, 0, 0, 0);
        }
#pragma unroll
        for (int i = 0; i < 4; i++) {
            int row = w * 16 + hi * 4 + i;
            float v = acc[i];
            if (DOEXP) v = __expf(fminf(v, 30.0f));
            outbase[(size_t)row * out_stride + t * 16 + cl] = v;
        }
        asm volatile("s_waitcnt vmcnt(0)" ::: "memory");
        __syncthreads();
        buf ^= 1;
    }
}

// ================= mega-kernels =================

__global__ void __launch_bounds__(256) megaA(
        const float* Gf, const float* Gb, const ushort* PMf, const ushort* PMb,
        float* hof, float* hob, float* hfin, uint* pk,
        const int* tgt, const float* emb, const float4* PdW, const float* dbias,
        float* Gd0) {
    __shared__ __align__(16) char smem[17152];
    int blk = blockIdx.x;
    if (blk < 16) enc_scan_body(blk, smem, Gf, Gb, PMf, PMb, hof, hob, hfin, pk);
    else dec0_body(blk - 16, smem, tgt, emb, PdW, dbias, Gd0);
}

__global__ void __launch_bounds__(256) enc_pscan3(
        const float* Gf, const float* Gb, const ushort* PMf, const ushort* PMb,
        float* hof, float* hob, float* hfin, uint* pk) {
    __shared__ __align__(16) char smem[17152];
    enc_scan_body(blockIdx.x, smem, Gf, Gb, PMf, PMb, hof, hob, hfin, pk);
}

// ---------------- dec_init2: compute h0[0] in f32, publish packets (tag 1) + c0a.
// grid 16 (b), 256 thr.
__global__ void __launch_bounds__(256) dec_init2(
        const float* __restrict__ Gd0, const float* __restrict__ dWhh0,
        const float* __restrict__ hinit, uint* __restrict__ h0pk,
        float* __restrict__ c0a) {
    __shared__ float hr[D];
    int b = blockIdx.x;
    int tid = threadIdx.x;
    hr[tid] = hinit[b * 512 + tid];
    hr[tid + 256] = hinit[b * 512 + tid + 256];
    __syncthreads();
#pragma unroll
    for (int half = 0; half < 2; half++) {
        int u = tid + half * 256;
        float acc[4] = {0.f, 0.f, 0.f, 0.f};
#pragma unroll
        for (int g = 0; g < 4; g++) {
            const float* wr = dWhh0 + (size_t)(g * 512 + u) * 512;
            float s = 0.f;
#pragma unroll 4
            for (int k = 0; k < 512; k++) s += wr[k] * hr[k];
            acc[g] = s;
        }
        const float* gg = Gd0 + ((size_t)(0 * B + b)) * 2048 + u;
        float g0 = gg[0] + acc[0], g1 = gg[512] + acc[1];
        float g2 = gg[1024] + acc[2], g3 = gg[1536] + acc[3];
        float ig = sigm(g0), fg = sigm(g1), gt = tanhf(g2), og = sigm(g3);
        (void)fg;
        float c0 = ig * gt;                 // c_{-1} = 0
        float h00 = og * tanhf(c0);
        c0a[b * 512 + u] = c0;
        pstore(&h0pk[8192 + b * 512 + u], ((uint)(ushort)bf16s(h00) << 16) | 1u);
    }
}

// megaC: 0..31 dec scan; 32..63 h1-init publish; 64..2111 enchB; 2112..4159 enchT;
// 4160..5159 outproj.
__global__ void __launch_bounds__(256) megaC(
        const float* G0, const ushort* PM0, const ushort* PM1, const float* b1,
        uint* h0pk, uint* h1pk, const float* c0a, float* h1out,
        const float* hinit,
        const float* h1f, const float* h1b, ushort* enchB, ushort* enchT,
        const float* emb, const float* Wvoc, __hip_bfloat16* outT2) {
    __shared__ __align__(16) char smem[41728];
    int blk = blockIdx.x;
    if (blk < 32) dec_body(blk, smem, G0, PM0, PM1, b1, h0pk, h1pk, c0a, h1out);
    else if (blk < 64) {
        int idx = (blk - 32) * 256 + threadIdx.x;     // B*D = 8192
        pstore(&h1pk[8192 + idx],
               ((uint)(ushort)bf16s(hinit[B * D + idx]) << 16) | 1u);
    }
    else if (blk < 2112) encht2_body(blk - 64, h1f, h1b, enchB);
    else if (blk < 4160) encht2T_body(blk - 2112, h1f, h1b, enchT);
    else outproj_body(blk - 4160, smem, emb, Wvoc, outT2);
}

// ---------------- q projections: bf16 qe, bf16 qd, h1dB1 pack. grid T*B, 512 thr.
__global__ void qproj(const float* __restrict__ h1d, const float* __restrict__ Wenc,
                      const float* __restrict__ Wdec, ushort* __restrict__ qeb16,
                      ushort* __restrict__ qdb16, ushort* __restrict__ h1dB1) {
    int n = blockIdx.x;
    int o = threadIdx.x;
    __shared__ float hr[D];
    hr[o] = h1d[(size_t)n * D + o];
    __syncthreads();
    float ae = 0.f, ad = 0.f;
#pragma unroll 4
    for (int k = 0; k < D; k++) {
        float hk = hr[k];
        ae += hk * Wenc[k * D + o];
        ad += hk * Wdec[k * D + o];
    }
    int b = n & 15, t = n >> 4;
    size_t rowb = (size_t)(b * 128 + t) << 9;
    qeb16[rowb + o] = (ushort)bf16s(ae);
    qdb16[rowb + o] = (ushort)bf16s(ad);
    if (o < 64) {
        float4 v0 = *(const float4*)(hr + o * 8);
        float4 v1 = *(const float4*)(hr + o * 8 + 4);
        st_bf8(h1dB1 + ((size_t)b << 16) + o * 1024 + t * 8, v0, v1);
    }
}

// ---------------- h1dB2 pack: [b][o(u/8)=16][d(512)][8u]. grid 512, 256 thr.
__global__ void pack_h1dB2(const float* __restrict__ h1d, ushort* __restrict__ h1dB2) {
    int idx = blockIdx.x * 256 + threadIdx.x;
    int b = idx >> 13;
    int r = idx & 8191;
    int o = r >> 9, d = r & 511;
    float f[8];
#pragma unroll
    for (int j = 0; j < 8; j++)
        f[j] = h1d[((size_t)((o * 8 + j) * B + b)) * D + d];
    float4 v0 = {f[0], f[1], f[2], f[3]}, v1 = {f[4], f[5], f[6], f[7]};
    st_bf8(h1dB2 + ((size_t)b << 16) + o * 4096 + d * 8, v0, v1);
}

// ---------------- scoreAB: blk<16 escore (ew, fused exp); else dec QK^T (dsout).
__global__ void __launch_bounds__(512) scoreAB(
        const ushort* __restrict__ qeb16, const ushort* __restrict__ enchB,
        float* __restrict__ ew,
        const ushort* __restrict__ qdb16, const ushort* __restrict__ h1dB1,
        float* __restrict__ dsout) {
    __shared__ __align__(16) char smem[32768];
    int blk = blockIdx.x;
    if (blk < 16) {
        int b = blk;
        gemm16_body<16, 32, 512, true>(smem,
            qeb16 + ((size_t)(b * 128) << 9), 512,
            enchB + ((size_t)b << 18),
            ew + (size_t)b * T * S, S);
    } else {
        int b = blk - 16;
        gemm16_body<16, 8, 128, false>(smem,
            qdb16 + ((size_t)(b * 128) << 9), 512,
            h1dB1 + ((size_t)b << 16),
            dsout + ((size_t)(b * 128)) * 128, 128);
    }
}

// ---------------- temporal normalization (prefix over t)
__global__ void temporal_k(float* __restrict__ ew) {
    int i = blockIdx.x * blockDim.x + threadIdx.x;
    if (i >= B * S) return;
    int b = i / S, sx = i - b * S;
    float cum = 0.f;
    for (int t = 0; t < T; t++) {
        size_t idx = ((size_t)(b * T + t)) * S + sx;
        float v = ew[idx];
        ew[idx] = v / (t == 0 ? 1.0f : (cum + 1e-8f));
        cum += v;
    }
}

// ---------------- smAB: blk<2048 enc softmax+copy (awb16); else dec softmax (pdb16).
__global__ void __launch_bounds__(512) smAB(
        const float* __restrict__ ew, const int* __restrict__ ids,
        const int* __restrict__ tgt, ushort* __restrict__ awb16,
        float* __restrict__ copyp,
        const float* __restrict__ dsout, ushort* __restrict__ pdb16) {
    __shared__ float red[512];
    int blk = blockIdx.x;
    int tid = threadIdx.x;
    if (blk < 2048) {
        int bt = blk;
        int b = bt >> 7, t = bt & 127;
        float v = ew[(size_t)bt * S + tid];
        int tok = ids[b * S + tid];
        bool pad = (tok == PAD_ID);
        float vm = pad ? -INFINITY : v;
        red[tid] = vm; __syncthreads();
        for (int w = 256; w > 0; w >>= 1) { if (tid < w) red[tid] = fmaxf(red[tid], red[tid + w]); __syncthreads(); }
        float m = red[0]; __syncthreads();
        float ex = pad ? 0.f : __expf(vm - m);
        red[tid] = ex; __syncthreads();
        for (int w = 256; w > 0; w >>= 1) { if (tid < w) red[tid] += red[tid + w]; __syncthreads(); }
        float Z = red[0]; __syncthreads();
        float a = ex / Z;
        int nt = tgt[b * T + t];
        red[tid] = (tok == nt) ? a : 0.f; __syncthreads();
        for (int w = 256; w > 0; w >>= 1) { if (tid < w) red[tid] += red[tid + w]; __syncthreads(); }
        if (tid == 0) copyp[bt] = red[0];
        awb16[(size_t)bt * S + tid] = (ushort)bf16s(a);
    } else {
        int bt2 = blk - 2048;
        int t = bt2 & 127;
        float sc = -INFINITY;
        if (tid < 128 && tid < t) sc = dsout[(size_t)bt2 * 128 + tid];
        if (tid < 128) red[tid] = sc;
        __syncthreads();
        for (int w = 64; w > 0; w >>= 1) { if (tid < w) red[tid] = fmaxf(red[tid], red[tid + w]); __syncthreads(); }
        float m = red[0]; __syncthreads();
        float ex = (tid < 128 && tid < t) ? __expf(sc - m) : 0.f;
        if (tid < 128) red[tid] = ex;
        __syncthreads();
        for (int w = 64; w > 0; w >>= 1) { if (tid < w) red[tid] += red[tid + w]; __syncthreads(); }
        float Z = red[0];
        if (tid < 128) pdb16[(size_t)bt2 * 128 + tid] = (ushort)bf16s((t > 0) ? ex / Z : 0.f);
    }
}

// ---------------- ctxAB: blk<16 ectx = aw @ ench; else dctx = P @ h1d.
__global__ void __launch_bounds__(512) ctxAB(
        const ushort* __restrict__ awb16, const ushort* __restrict__ enchT,
        float* __restrict__ ectx,
        const ushort* __restrict__ pdb16, const ushort* __restrict__ h1dB2,
        float* __restrict__ dctx) {
    __shared__ __align__(16) char smem[32768];
    int blk = blockIdx.x;
    if (blk < 16) {
        int b = blk;
        gemm16_body<16, 32, 512, false>(smem,
            awb16 + ((size_t)(b * 128)) * 512, 512,
            enchT + ((size_t)b << 18),
            ectx + ((size_t)(b * 128)) * 512, 512);
    } else {
        int b = blk - 16;
        gemm16_body<4, 32, 512, false>(smem,
            pdb16 + ((size_t)(b * 128)) * 128, 128,
            h1dB2 + ((size_t)b << 16),
            dctx + ((size_t)(b * 128)) * 512, 512);
    }
}

// ---------------- concat + p_gen; writes bf16 ccb16. grid B*T, 512 thr
__global__ void concat_k(const float* __restrict__ h1d, const float* __restrict__ ectx,
                         const float* __restrict__ dctx, const float* __restrict__ sW,
                         const float* __restrict__ sb, ushort* __restrict__ ccb16,
                         float* __restrict__ pgen) {
    int bt = blockIdx.x;
    int b = bt / T, t = bt - b * T;
    int d = threadIdx.x;
    __shared__ float red[512];
    float v0 = h1d[((size_t)(t * B + b)) * D + d];
    float v1 = ectx[(size_t)bt * D + d];
    float v2 = dctx[(size_t)bt * D + d];
    ushort* c = ccb16 + (size_t)bt * C3;
    c[d] = (ushort)bf16s(v0); c[D + d] = (ushort)bf16s(v1); c[2 * D + d] = (ushort)bf16s(v2);
    red[d] = v0 * sW[d] + v1 * sW[D + d] + v2 * sW[2 * D + d];
    __syncthreads();
    for (int w = 256; w > 0; w >>= 1) { if (d < w) red[d] += red[d + w]; __syncthreads(); }
    if (d == 0) pgen[bt] = 1.f / (1.f + __expf(-(red[0] + sb[0])));
}

// ---------------- vocab GEMM: register-A (M=128), LDS dbuf B stream (passing).
__global__ void __launch_bounds__(512) vocab_mfma3(
        const __hip_bfloat16* __restrict__ outT2, const ushort* __restrict__ ccb16,
        const float* __restrict__ ob, const int* __restrict__ tgt,
        float* __restrict__ pbuf) {
    __shared__ __align__(16) ushort Bs[2][3072 * 8];
    __shared__ int jstar_s[128];
    int bid = blockIdx.x;
    int rb = bid & 15, jg = bid >> 4;
    int row0 = rb * 128;
    int tid = threadIdx.x;
    int lane = tid & 63, w = tid >> 6;
    int cl = lane & 15, hi = lane >> 4;
    int j0base = jg * 2000;

    if (tid < 128) {
        int nt = tgt[row0 + tid];
        int ix = nt - 3;
        ix = ix < 0 ? 0 : (ix > VO - 1 ? VO - 1 : ix);
        jstar_s[tid] = ix;
    }
    short8 a[48];
    {
        const ushort* asrc = ccb16 + (size_t)(row0 + w * 16 + cl) * C3 + hi * 8;
#pragma unroll
        for (int kt = 0; kt < 48; kt++) a[kt] = *(const short8*)(asrc + kt * 32);
    }
    {
#pragma unroll
        for (int ii = 0; ii < 6; ii++) {
            int c = w * 384 + ii * 64 + lane;
            int o = c >> 4, jl = c & 15;
            const char* g = (const char*)outT2 + ((size_t)o * JS + (size_t)(j0base + jl)) * 16;
            gload_lds16(g, (char*)&Bs[0][0] + (size_t)(w * 384 + ii * 64) * 16);
        }
    }
    asm volatile("s_waitcnt vmcnt(0)" ::: "memory");
    __syncthreads();
    int jst[4];
    float m[4], sacc[4], gl[4];
#pragma unroll
    for (int i = 0; i < 4; i++) {
        jst[i] = jstar_s[w * 16 + hi * 4 + i];
        m[i] = -1e30f; sacc[i] = 0.f; gl[i] = -1e30f;
    }
    int buf = 0;
    for (int t = 0; t < 125; t++) {
        if (t + 1 < 125) {
            int j0 = j0base + (t + 1) * 16;
#pragma unroll
            for (int ii = 0; ii < 6; ii++) {
                int c = w * 384 + ii * 64 + lane;
                int o = c >> 4, jl = c & 15;
                const char* g = (const char*)outT2 + ((size_t)o * JS + (size_t)(j0 + jl)) * 16;
                gload_lds16(g, (char*)&Bs[buf ^ 1][0] + (size_t)(w * 384 + ii * 64) * 16);
            }
        }
        f32x4 acc = {0.f, 0.f, 0.f, 0.f};
        const ushort* bp = &Bs[buf][0] + (size_t)(hi * 16 + cl) * 8;
#pragma unroll
        for (int kt = 0; kt < 48; kt++) {
            short8 b = *(const short8*)(bp + (size_t)kt * 512);
            acc = __builtin_amdgcn_mfma_f32_16x16x32_bf16(a[kt], b, acc, 0, 0, 0);
        }
        int j = j0base + t * 16 + cl;
        bool valid = j < VO;
        float obj = valid ? ob[j] : 0.f;
#pragma unroll
        for (int i = 0; i < 4; i++) {
            float L = acc[i] + obj;
            if (valid) {
                if (j == jst[i]) gl[i] = L;
                float mn = fmaxf(m[i], L);
                sacc[i] = sacc[i] * __expf(m[i] - mn) + __expf(L - mn);
                m[i] = mn;
            }
        }
        asm volatile("s_waitcnt vmcnt(0)" ::: "memory");
        __syncthreads();
        buf ^= 1;
    }
#pragma unroll
    for (int i = 0; i < 4; i++) {
        for (int mask = 1; mask < 16; mask <<= 1) {
            float om = __shfl_xor(m[i], mask);
            float os = __shfl_xor(sacc[i], mask);
            float mn = fmaxf(m[i], om);
            sacc[i] = sacc[i] * __expf(m[i] - mn) + os * __expf(om - mn);
            m[i] = mn;
            gl[i] = fmaxf(gl[i], __shfl_xor(gl[i], mask));
        }
    }
    if (cl == 0) {
#pragma unroll
        for (int i = 0; i < 4; i++) {
            int rl = w * 16 + hi * 4 + i;
            float* o = pbuf + ((size_t)(jg * 16 + rb) * 128 + rl) * 4;
            o[0] = m[i]; o[1] = sacc[i]; o[2] = gl[i];
        }
    }
}

// ---------------- combine 16 jg-partials + pointer mix + NLL. grid B, 128 threads.
__global__ void combine_nll_k(const float* __restrict__ pbuf, const int* __restrict__ tgt,
                              const float* __restrict__ pgen, const float* __restrict__ copyp,
                              const int* __restrict__ tlen, float* __restrict__ out) {
    int b = blockIdx.x, t = threadIdx.x;
    int row = b * T + t;
    int rb = row >> 7, rl = row & 127;
    float M = -1e30f, SS = 0.f, GL = -1e30f;
#pragma unroll
    for (int q = 0; q < 16; q++) {
        const float* p = pbuf + ((size_t)(q * 16 + rb) * 128 + rl) * 4;
        float mq = p[0], sq = p[1], gq = p[2];
        float mn = fmaxf(M, mq);
        SS = SS * __expf(M - mn) + sq * __expf(mq - mn);
        M = mn;
        GL = fmaxf(GL, gq);
    }
    int nt = tgt[row];
    float genp = (nt >= 3 && nt < V) ? __expf(GL - M) / SS : 0.f;
    float pg = pgen[row];
    float p = pg * genp + (1.f - pg) * copyp[row];
    __shared__ float red[128];
    red[t] = (t < tlen[b]) ? -logf(p + 1e-9f) : 0.f;
    __syncthreads();
    for (int w = 64; w > 0; w >>= 1) { if (t < w) red[t] += red[t + w]; __syncthreads(); }
    if (t == 0) out[b] = red[0];
}

extern "C" void kernel_launch(void* const* d_in, const int* in_sizes, int n_in,
                              void* d_out, int out_size, void* d_ws, size_t ws_size,
                              hipStream_t stream) {
    const int* input_ids = (const int*)d_in[0];
    const int* target_ids = (const int*)d_in[1];
    const int* tlen = (const int*)d_in[3];
    const float* emb = (const float*)d_in[5];
    const float* eWih0f = (const float*)d_in[6],  *eWhh0f = (const float*)d_in[7],  *eb0f = (const float*)d_in[8];
    const float* eWih0b = (const float*)d_in[9],  *eWhh0b = (const float*)d_in[10], *eb0b = (const float*)d_in[11];
    const float* eWih1f = (const float*)d_in[12], *eWhh1f = (const float*)d_in[13], *eb1f = (const float*)d_in[14];
    const float* eWih1b = (const float*)d_in[15], *eWhh1b = (const float*)d_in[16], *eb1b = (const float*)d_in[17];
    const float* dWih0 = (const float*)d_in[18], *dWhh0 = (const float*)d_in[19], *db0 = (const float*)d_in[20];
    const float* dWih1 = (const float*)d_in[21], *dWhh1 = (const float*)d_in[22], *db1 = (const float*)d_in[23];
    const float* Wenc = (const float*)d_in[24], *Wdec = (const float*)d_in[25];
    const float* Wvoc = (const float*)d_in[26], *sW = (const float*)d_in[27], *sb = (const float*)d_in[28];
    const float* ob = (const float*)d_in[29];
    float* out = (float*)d_out;
    (void)ws_size; (void)n_in; (void)in_sizes; (void)out_size;

    // ============ workspace layout (~193.4 MB, phase-aliased) ============
    char* A = (char*)d_ws;
    float4* pWih0f = (float4*)(A + 0);
    float4* pWih0b = (float4*)(A + 524288);
    ushort* PMW1f  = (ushort*)(A + 1048576);
    ushort* PMW1b  = (ushort*)(A + 2097152);
    float4* pdWih0 = (float4*)(A + 5242880);
    ushort* PMf0  = (ushort*)(A + 6291456);
    ushort* PMb0  = (ushort*)(A + 6815744);
    ushort* PMf1  = (ushort*)(A + 7340032);
    ushort* PMb1  = (ushort*)(A + 7864320);
    float* G0f = (float*)(A + 23068672);
    float* G0b = (float*)(A + 56623104);
    __hip_bfloat16* outT2 = (__hip_bfloat16*)A;     // whole region (megaC)

    char* Bh = A + 98304000;
    float* h0f = (float*)(Bh + 0);
    float* h0b = (float*)(Bh + 8388608);
    float* h1d = (float*)(Bh + 0);
    ushort* qeb16 = (ushort*)(Bh + 4194304);
    ushort* awb16 = (ushort*)(Bh + 6291456);
    ushort* qdb16 = (ushort*)(Bh + 8388608);
    ushort* h1dB1 = (ushort*)(Bh + 10485760);
    float* ew  = (float*)(Bh + 12582912);
    float* pbuf = (float*)(Bh + 12582912);

    char* Cr = Bh + 16777216;
    float* h1f = (float*)(Cr + 0);
    float* h1b = (float*)(Cr + 8388608);
    ushort* ccb16 = (ushort*)(Cr + 16777216);
    float*  dsout = (float*)(Cr + 23068672);
    ushort* pdb16 = (ushort*)(Cr + 24117248);
    ushort* h1dB2 = (ushort*)(Cr + 24641536);
    float* dec_init = (float*)(Cr + 29360128);
    float* pgen  = (float*)(Cr + 29425664);
    float* copyp = (float*)(Cr + 29433856);
    uint* hpkE0  = (uint*)(Cr + 29769728);
    uint* hpkE1  = (uint*)(Cr + 29835264);
    uint* h0pkD  = (uint*)(Cr + 29900800);
    uint* h1pkD  = (uint*)(Cr + 29966336);

    char* X = Cr + 30031872;
    float*  Gd0x  = (float*)(X + 0);
    ushort* PM0x  = (ushort*)(X + 16777216);
    ushort* PM1x  = (ushort*)(X + 18874368);
    ushort* enchB = (ushort*)(X + 23068672);
    float*  ectx  = (float*)(X + 31457280);
    float*  dctx  = (float*)(X + 35651584);
    ushort* enchT = (ushort*)(X + 39845888);
    float*  c0a   = (float*)(X + 48234496);         // 32 KB
    // total ≈ 193,380,352 B

    hipMemsetAsync(hpkE0, 0, 262144, stream);

    auto pack = [&](const float* W, float4* P, int Hn, int K) {
        int total = Hn * K;
        hipLaunchKernelGGL(pack4_kernel, dim3((total + 255) / 256), dim3(256), 0, stream, W, P, Hn, K);
    };
    pack(eWih0f, pWih0f, H, E);
    pack(eWih0b, pWih0b, H, E);
    pack(dWih0, pdWih0, D, E);
    hipLaunchKernelGGL(packencMK_k, dim3(4 * H * 256 / 256), dim3(256), 0, stream, eWhh0f, PMf0, 256);
    hipLaunchKernelGGL(packencMK_k, dim3(4 * H * 256 / 256), dim3(256), 0, stream, eWhh0b, PMb0, 256);
    hipLaunchKernelGGL(packencMK_k, dim3(4 * H * 256 / 256), dim3(256), 0, stream, eWhh1f, PMf1, 256);
    hipLaunchKernelGGL(packencMK_k, dim3(4 * H * 256 / 256), dim3(256), 0, stream, eWhh1b, PMb1, 256);
    hipLaunchKernelGGL(packencMK_k, dim3(4 * H * 512 / 256), dim3(256), 0, stream, eWih1f, PMW1f, 512);
    hipLaunchKernelGGL(packencMK_k, dim3(4 * H * 512 / 256), dim3(256), 0, stream, eWih1b, PMW1b, 512);
    hipLaunchKernelGGL(packdecM_k, dim3(4 * D * D / 256), dim3(256), 0, stream, dWhh0, PM0x);
    hipLaunchKernelGGL(packdecM2_k, dim3(8 * D * D / 256), dim3(256), 0, stream, dWih1, dWhh1, PM1x);

    hipLaunchKernelGGL(enc0_gates2, dim3(S * B / 8), dim3(256), 0, stream,
                       input_ids, emb, pWih0f, eb0f, pWih0b, eb0b, G0f, G0b);
    hipLaunchKernelGGL(megaA, dim3(272), dim3(256), 0, stream,
                       G0f, G0b, PMf0, PMb0, h0f, h0b, dec_init, hpkE0,
                       target_ids, emb, pdWih0, db0, Gd0x);
    // h0[0] bootstrap: needs Gd0x + dec_init (both from megaA); overlaps enc L1 below
    hipLaunchKernelGGL(dec_init2, dim3(16), dim3(256), 0, stream,
                       Gd0x, dWhh0, dec_init, h0pkD, c0a);
    hipLaunchKernelGGL(enc1g_mfma, dim3(256), dim3(256), 0, stream,
                       h0f, h0b, PMW1f, PMW1b, eb1f, eb1b, G0f, G0b);
    hipLaunchKernelGGL(enc_pscan3, dim3(16), dim3(256), 0, stream,
                       G0f, G0b, PMf1, PMb1, h1f, h1b, dec_init + B * D, hpkE1);
    hipLaunchKernelGGL(megaC, dim3(5160), dim3(256), 0, stream,
                       Gd0x, PM0x, PM1x, db1, h0pkD, h1pkD, c0a, h1d,
                       dec_init, h1f, h1b, enchB, enchT, emb, Wvoc, outT2);
    hipLaunchKernelGGL(qproj, dim3(T * B), dim3(D), 0, stream,
                       h1d, Wenc, Wdec, qeb16, qdb16, h1dB1);
    hipLaunchKernelGGL(pack_h1dB2, dim3(512), dim3(256), 0, stream, h1d, h1dB2);
    hipLaunchKernelGGL(scoreAB, dim3(32), dim3(512), 0, stream,
                       qeb16, enchB, ew, qdb16, h1dB1, dsout);
    hipLaunchKernelGGL(temporal_k, dim3((B * S + 255) / 256), dim3(256), 0, stream, ew);
    hipLaunchKernelGGL(smAB, dim3(4096), dim3(512), 0, stream,
                       ew, input_ids, target_ids, awb16, copyp, dsout, pdb16);
    hipLaunchKernelGGL(ctxAB, dim3(32), dim3(512), 0, stream,
                       awb16, enchT, ectx, pdb16, h1dB2, dctx);
    hipLaunchKernelGGL(concat_k, dim3(B * T), dim3(D), 0, stream,
                       h1d, ectx, dctx, sW, sb, ccb16, pgen);
    hipLaunchKernelGGL(vocab_mfma3, dim3(256), dim3(512), 0, stream,
                       outT2, ccb16, ob, target_ids, pbuf);
    hipLaunchKernelGGL(combine_nll_k, dim3(B), dim3(T), 0, stream,
                       pbuf, target_ids, pgen, copyp, tlen, out);
}

// Round 18
// 3775.458 us; speedup vs baseline: 6.0946x; 1.0601x over previous
//
#include <hip/hip_runtime.h>
#include <hip/hip_bf16.h>
#include <math.h>

#define PAD_ID 0
#define UNK_ID 1
#define START_ID 2
#define END_ID 3

constexpr int B = 16, S = 512, T = 128, V = 32000, E = 128, H = 256, D = 512;
constexpr int C3 = 1536;        // 3*D
constexpr int VO = 31997;       // V-3
constexpr int JS = 32000;       // padded col count for outT2

typedef short short8 __attribute__((ext_vector_type(8)));
typedef float f32x4 __attribute__((ext_vector_type(4)));

__device__ __forceinline__ float sigm(float x) { return 1.0f / (1.0f + __expf(-x)); }
__device__ __forceinline__ short bf16s(float x) {
    __hip_bfloat16 h = __float2bfloat16(x);
    return *reinterpret_cast<short*>(&h);
}

__device__ __forceinline__ uint4 cloadu4(const uint* p) {
    uint4 v;
    asm volatile("global_load_dwordx4 %0, %1, off sc0 sc1" : "=v"(v) : "v"(p));
    return v;
}
__device__ __forceinline__ void pstore(uint* p, uint v) {
    __hip_atomic_store(p, v, __ATOMIC_RELAXED, __HIP_MEMORY_SCOPE_AGENT);
}

__device__ __forceinline__ void gload_lds16(const void* g, void* l) {
    __builtin_amdgcn_global_load_lds(
        (const __attribute__((address_space(1))) void*)(g),
        (__attribute__((address_space(3))) void*)(l), 16, 0, 0);
}

__device__ __forceinline__ void st_bf8(ushort* dst, float4 a, float4 b) {
    short8 o;
    o[0] = bf16s(a.x); o[1] = bf16s(a.y); o[2] = bf16s(a.z); o[3] = bf16s(a.w);
    o[4] = bf16s(b.x); o[5] = bf16s(b.y); o[6] = bf16s(b.z); o[7] = bf16s(b.w);
    *(short8*)dst = o;
}

// ---------------- poll 16 packets tagged e; write 16 bf16 to dst
__device__ __forceinline__ void poll_stage16(const uint* src, uint e, ushort* dst) {
    uint4 a0, a1, a2, a3;
    for (;;) {
        a0 = cloadu4(src); a1 = cloadu4(src + 4); a2 = cloadu4(src + 8); a3 = cloadu4(src + 12);
        asm volatile("s_waitcnt vmcnt(0)" ::: "memory");
        __builtin_amdgcn_sched_barrier(0);
        uint d = (a0.x ^ e) | (a0.y ^ e) | (a0.z ^ e) | (a0.w ^ e)
               | (a1.x ^ e) | (a1.y ^ e) | (a1.z ^ e) | (a1.w ^ e)
               | (a2.x ^ e) | (a2.y ^ e) | (a2.z ^ e) | (a2.w ^ e)
               | (a3.x ^ e) | (a3.y ^ e) | (a3.z ^ e) | (a3.w ^ e);
        if ((d & 0xffffu) == 0) break;
        __builtin_amdgcn_s_sleep(1);
    }
    short8 o0, o1;
    o0[0] = (short)(a0.x >> 16); o0[1] = (short)(a0.y >> 16); o0[2] = (short)(a0.z >> 16); o0[3] = (short)(a0.w >> 16);
    o0[4] = (short)(a1.x >> 16); o0[5] = (short)(a1.y >> 16); o0[6] = (short)(a1.z >> 16); o0[7] = (short)(a1.w >> 16);
    o1[0] = (short)(a2.x >> 16); o1[1] = (short)(a2.y >> 16); o1[2] = (short)(a2.z >> 16); o1[3] = (short)(a2.w >> 16);
    o1[4] = (short)(a3.x >> 16); o1[5] = (short)(a3.y >> 16); o1[6] = (short)(a3.z >> 16); o1[7] = (short)(a3.w >> 16);
    *(short8*)dst = o0;
    *(short8*)(dst + 8) = o1;
}

// ---------------- poll 32 packets tagged e; write 32 bf16 to dst
__device__ __forceinline__ void poll_stage32(const uint* src, uint e, ushort* dst) {
    uint4 a[8];
    for (;;) {
#pragma unroll
        for (int i = 0; i < 8; i++) a[i] = cloadu4(src + i * 4);
        asm volatile("s_waitcnt vmcnt(0)" ::: "memory");
        __builtin_amdgcn_sched_barrier(0);
        uint d = 0;
#pragma unroll
        for (int i = 0; i < 8; i++)
            d |= (a[i].x ^ e) | (a[i].y ^ e) | (a[i].z ^ e) | (a[i].w ^ e);
        if ((d & 0xffffu) == 0) break;
        __builtin_amdgcn_s_sleep(1);
    }
#pragma unroll
    for (int i = 0; i < 8; i += 2) {
        short8 o;
        o[0] = (short)(a[i].x >> 16);     o[1] = (short)(a[i].y >> 16);
        o[2] = (short)(a[i].z >> 16);     o[3] = (short)(a[i].w >> 16);
        o[4] = (short)(a[i + 1].x >> 16); o[5] = (short)(a[i + 1].y >> 16);
        o[6] = (short)(a[i + 1].z >> 16); o[7] = (short)(a[i + 1].w >> 16);
        *(short8*)(dst + i * 4) = o;
    }
}

// ---------------- weight packing: W[4H][K] -> P[k][u] = float4 of 4 gates
__global__ void pack4_kernel(const float* __restrict__ W, float4* __restrict__ P, int Hn, int K) {
    int i = blockIdx.x * blockDim.x + threadIdx.x;
    if (i >= K * Hn) return;
    int k = i / Hn, u = i - k * Hn;
    float4 v;
    v.x = W[(size_t)(0 * Hn + u) * K + k];
    v.y = W[(size_t)(1 * Hn + u) * K + k];
    v.z = W[(size_t)(2 * Hn + u) * K + k];
    v.w = W[(size_t)(3 * Hn + u) * K + k];
    P[(size_t)k * Hn + u] = v;
}

// ---------------- MFMA-row pack (H=256 outputs): row = (u>>3)*32 + g*8 + (u&7)
__global__ void packencMK_k(const float* __restrict__ W, ushort* __restrict__ P, int K) {
    int i = blockIdx.x * blockDim.x + threadIdx.x;
    if (i >= 4 * H * K) return;
    int k = i % K, row = i / K;
    int g = (row >> 3) & 3, ul = row & 7, uh = row >> 5;
    int u = uh * 8 + ul;
    P[i] = (ushort)bf16s(W[(size_t)(g * H + u) * K + k]);
}

// ---------------- decoder W0 pack for MFMA (row = bk*64 + g*16 + u%16)
__global__ void packdecM_k(const float* __restrict__ W, ushort* __restrict__ P) {
    int i = blockIdx.x * blockDim.x + threadIdx.x;
    if (i >= 4 * D * D) return;
    int k = i & 511, row = i >> 9;
    int g = (row >> 4) & 3, u = (row >> 6) * 16 + (row & 15);
    P[i] = (ushort)bf16s(W[(size_t)(g * D + u) * D + k]);
}

// ---------------- decoder layer1 pack: [W1i | W1h] -> PM1[row][1024] bf16
__global__ void packdecM2_k(const float* __restrict__ Wi, const float* __restrict__ Wh,
                            ushort* __restrict__ P) {
    int i = blockIdx.x * blockDim.x + threadIdx.x;
    if (i >= 4 * D * D * 2) return;
    int k = i & 1023, row = i >> 10;
    int g = (row >> 4) & 3, u = (row >> 6) * 16 + (row & 15);
    float v = (k < 512) ? Wi[(size_t)(g * D + u) * D + k]
                        : Wh[(size_t)(g * D + u) * D + (k - 512)];
    P[i] = (ushort)bf16s(v);
}

// ---------------- encoder layer-0 gates, tiled (8 rows/block). grid S*B/8, 256 thr.
__global__ void enc0_gates2(const int* __restrict__ ids, const float* __restrict__ emb,
                            const float4* __restrict__ Pf, const float* __restrict__ bf_,
                            const float4* __restrict__ Pb, const float* __restrict__ bb_,
                            float* __restrict__ Gf, float* __restrict__ Gb) {
    int n0 = blockIdx.x * 8;
    int u = threadIdx.x;
    __shared__ float xr[8][E];
    for (int i = u; i < 8 * E; i += 256) {
        int r = i >> 7, e = i & 127;
        int n = n0 + r, s = n / B, b = n - s * B;
        int tok = ids[b * S + s];
        if (tok >= V) tok = UNK_ID;
        xr[r][e] = emb[(size_t)tok * E + e];
    }
    __syncthreads();
#pragma unroll
    for (int dir = 0; dir < 2; dir++) {
        const float4* P = dir ? Pb : Pf;
        const float* bs = dir ? bb_ : bf_;
        float* G = dir ? Gb : Gf;
        float acc[8][4];
#pragma unroll
        for (int r = 0; r < 8; r++)
#pragma unroll
            for (int g = 0; g < 4; g++) acc[r][g] = 0.f;
#pragma unroll 4
        for (int k = 0; k < E; k++) {
            float4 w = P[k * H + u];
#pragma unroll
            for (int r = 0; r < 8; r++) {
                float x = xr[r][k];
                acc[r][0] += x * w.x; acc[r][1] += x * w.y;
                acc[r][2] += x * w.z; acc[r][3] += x * w.w;
            }
        }
        float b0 = bs[u], b1 = bs[H + u], b2 = bs[2 * H + u], b3 = bs[3 * H + u];
#pragma unroll
        for (int r = 0; r < 8; r++) {
            float* g = G + (size_t)(n0 + r) * (4 * H);
            g[u] = acc[r][0] + b0; g[H + u] = acc[r][1] + b1;
            g[2 * H + u] = acc[r][2] + b2; g[3 * H + u] = acc[r][3] + b3;
        }
    }
}

// ---------------- encoder layer-1 gates via MFMA. grid 256, 256 thr.
__global__ void __launch_bounds__(256) enc1g_mfma(
        const float* __restrict__ h0f, const float* __restrict__ h0b,
        const ushort* __restrict__ PMf, const ushort* __restrict__ PMb,
        const float* __restrict__ bf_, const float* __restrict__ bb_,
        float* __restrict__ Gf, float* __restrict__ Gb) {
    __shared__ __align__(16) ushort X[16 * 520];
    __shared__ float gs[4][32][17];
    __shared__ float bias_s[128];
    int bid = blockIdx.x;
    int dirb = (bid >> 3) & 1, bk = bid & 7, ns = bid >> 4;
    const ushort* PM = dirb ? PMb : PMf;
    const float* bs = dirb ? bb_ : bf_;
    float* G = dirb ? Gb : Gf;
    int tid = threadIdx.x;
    int lane = tid & 63, w = tid >> 6;
    int cl = lane & 15, hi = lane >> 4;

    short8 afr[2][16];
    {
        int rowbase = (bk * 4 + w) * 32;
#pragma unroll
        for (int mt = 0; mt < 2; mt++)
#pragma unroll
            for (int kt = 0; kt < 16; kt++)
                afr[mt][kt] = *(const short8*)(PM + (size_t)(rowbase + mt * 16 + cl) * 512 + kt * 32 + hi * 8);
    }
    if (tid < 128) {
        int g = (tid >> 3) & 3;
        int u = (bk * 4 + (tid >> 5)) * 8 + (tid & 7);
        bias_s[tid] = bs[g * H + u];
    }
    int nl = tid >> 4, kseg = tid & 15;
    int en = tid & 15, rgrp = tid >> 4;
    for (int tt = 0; tt < 32; tt++) {
        int nt = ns * 32 + tt;
        __syncthreads();
        {
            int n = nt * 16 + nl;
            const float* src = (kseg < 8) ? (h0f + (size_t)n * H + kseg * 32)
                                          : (h0b + (size_t)n * H + (kseg - 8) * 32);
            float4 v0 = *(const float4*)(src), v1 = *(const float4*)(src + 4);
            float4 v2 = *(const float4*)(src + 8), v3 = *(const float4*)(src + 12);
            float4 v4 = *(const float4*)(src + 16), v5 = *(const float4*)(src + 20);
            float4 v6 = *(const float4*)(src + 24), v7 = *(const float4*)(src + 28);
            ushort* dst = X + nl * 520 + kseg * 32;
            st_bf8(dst, v0, v1); st_bf8(dst + 8, v2, v3);
            st_bf8(dst + 16, v4, v5); st_bf8(dst + 24, v6, v7);
        }
        __syncthreads();
        {
            f32x4 acc0 = {0.f, 0.f, 0.f, 0.f}, acc1 = {0.f, 0.f, 0.f, 0.f};
            const ushort* hp = X + cl * 520 + hi * 8;
#pragma unroll
            for (int kt = 0; kt < 16; kt++) {
                short8 bfr = *(const short8*)(hp + kt * 32);
                acc0 = __builtin_amdgcn_mfma_f32_16x16x32_bf16(afr[0][kt], bfr, acc0, 0, 0, 0);
                acc1 = __builtin_amdgcn_mfma_f32_16x16x32_bf16(afr[1][kt], bfr, acc1, 0, 0, 0);
            }
#pragma unroll
            for (int i = 0; i < 4; i++) {
                gs[w][hi * 4 + i][cl] = acc0[i];
                gs[w][16 + hi * 4 + i][cl] = acc1[i];
            }
        }
        __syncthreads();
        {
            int wv = rgrp >> 2, g = rgrp & 3;
            int u0 = (bk * 4 + wv) * 8;
            float* dst = G + (size_t)(nt * 16 + en) * 1024 + g * 256 + u0;
            float4 o0, o1;
            o0.x = gs[wv][g * 8 + 0][en] + bias_s[rgrp * 8 + 0];
            o0.y = gs[wv][g * 8 + 1][en] + bias_s[rgrp * 8 + 1];
            o0.z = gs[wv][g * 8 + 2][en] + bias_s[rgrp * 8 + 2];
            o0.w = gs[wv][g * 8 + 3][en] + bias_s[rgrp * 8 + 3];
            o1.x = gs[wv][g * 8 + 4][en] + bias_s[rgrp * 8 + 4];
            o1.y = gs[wv][g * 8 + 5][en] + bias_s[rgrp * 8 + 5];
            o1.z = gs[wv][g * 8 + 6][en] + bias_s[rgrp * 8 + 6];
            o1.w = gs[wv][g * 8 + 7][en] + bias_s[rgrp * 8 + 7];
            *(float4*)dst = o0;
            *(float4*)(dst + 4) = o1;
        }
    }
}

// ================= device bodies =================

// ---- enc scan body (dataflow packets). blk in [0,16).
__device__ __forceinline__ void enc_scan_body(int blk, char* smem,
        const float* __restrict__ Gf, const float* __restrict__ Gb,
        const ushort* __restrict__ PMf, const ushort* __restrict__ PMb,
        float* __restrict__ hof, float* __restrict__ hob,
        float* __restrict__ hfin, uint* __restrict__ pk) {
    ushort* hh = (ushort*)smem;
    float (*gs)[32][17] = (float(*)[32][17])(smem + 8448);
    int dirb = blk >> 3, bk = blk & 7;
    const float* G = dirb ? Gb : Gf;
    const ushort* PM = dirb ? PMb : PMf;
    float* ho = dirb ? hob : hof;
    int tid = threadIdx.x;
    int lane = tid & 63, w = tid >> 6;
    int cl = lane & 15, hi = lane >> 4;

    short8 afr[2][8];
    {
        int rowbase = (bk * 4 + w) * 32;
#pragma unroll
        for (int mt = 0; mt < 2; mt++)
#pragma unroll
            for (int kt = 0; kt < 8; kt++)
                afr[mt][kt] = *(const short8*)(PM + (size_t)(rowbase + mt * 16 + cl) * 256 + kt * 32 + hi * 8);
    }
    int ub = tid & 31, bb = tid >> 5;
    int u_glob = bk * 32 + ub;
    int gsw = ub >> 3, ul = ub & 7;
    float c_a = 0.f, c_b = 0.f;
    int b0s = tid >> 4, u0s = (tid & 15) * 16;

    for (int step = 0; step < S; step++) {
        int s = dirb ? (S - 1 - step) : step;
        int cur = step & 1;
        const float* gA = G + ((size_t)(s * B + bb)) * 1024 + u_glob;
        const float* gB = G + ((size_t)(s * B + bb + 8)) * 1024 + u_glob;
        float pa0 = gA[0], pa1 = gA[256], pa2 = gA[512], pa3 = gA[768];
        float pb0 = gB[0], pb1 = gB[256], pb2 = gB[512], pb3 = gB[768];
        poll_stage16(pk + cur * 8192 + dirb * 4096 + tid * 16,
                     (uint)step & 0xffffu, hh + b0s * 264 + u0s);
        __syncthreads();
        {
            f32x4 acc0 = {0.f, 0.f, 0.f, 0.f}, acc1 = {0.f, 0.f, 0.f, 0.f};
            const ushort* hp = hh + cl * 264 + hi * 8;
#pragma unroll
            for (int kt = 0; kt < 8; kt++) {
                short8 bfr = *(const short8*)(hp + kt * 32);
                acc0 = __builtin_amdgcn_mfma_f32_16x16x32_bf16(afr[0][kt], bfr, acc0, 0, 0, 0);
                acc1 = __builtin_amdgcn_mfma_f32_16x16x32_bf16(afr[1][kt], bfr, acc1, 0, 0, 0);
            }
#pragma unroll
            for (int i = 0; i < 4; i++) {
                gs[w][hi * 4 + i][cl] = acc0[i];
                gs[w][16 + hi * 4 + i][cl] = acc1[i];
            }
        }
        __syncthreads();
        {
            float q0 = gs[gsw][0 + ul][bb];
            float q1 = gs[gsw][8 + ul][bb];
            float q2 = gs[gsw][16 + ul][bb];
            float q3 = gs[gsw][24 + ul][bb];
            float ig = sigm(pa0 + q0), fg = sigm(pa1 + q1), gt = tanhf(pa2 + q2), og = sigm(pa3 + q3);
            c_a = fg * c_a + ig * gt;
            float hA = og * tanhf(c_a);
            q0 = gs[gsw][0 + ul][bb + 8];
            q1 = gs[gsw][8 + ul][bb + 8];
            q2 = gs[gsw][16 + ul][bb + 8];
            q3 = gs[gsw][24 + ul][bb + 8];
            ig = sigm(pb0 + q0); fg = sigm(pb1 + q1); gt = tanhf(pb2 + q2); og = sigm(pb3 + q3);
            c_b = fg * c_b + ig * gt;
            float hB = og * tanhf(c_b);
            uint tg = (uint)(step + 1) & 0xffffu;
            uint* dstp = pk + (cur ^ 1) * 8192 + dirb * 4096;
            pstore(&dstp[bb * 256 + u_glob], ((uint)(ushort)bf16s(hA) << 16) | tg);
            pstore(&dstp[(bb + 8) * 256 + u_glob], ((uint)(ushort)bf16s(hB) << 16) | tg);
            ho[((size_t)(s * B + bb)) * H + u_glob] = hA;
            ho[((size_t)(s * B + bb + 8)) * H + u_glob] = hB;
            if (step == S - 1) {
                hfin[bb * (2 * H) + dirb * H + u_glob] = hA;
                hfin[(bb + 8) * (2 * H) + dirb * H + u_glob] = hB;
            }
        }
    }
}

// ---- dec0 gates body
__device__ __forceinline__ void dec0_body(int bid, char* smem,
        const int* __restrict__ tgt, const float* __restrict__ emb,
        const float4* __restrict__ P, const float* __restrict__ bias,
        float* __restrict__ G) {
    float (*xr)[E] = (float(*)[E])smem;
    int n0 = bid * 8;
    int tid = threadIdx.x;
    for (int i = tid; i < 8 * E; i += 256) {
        int r = i >> 7, e = i & 127;
        int n = n0 + r, t = n / B, b = n - t * B;
        int tok;
        if (t == 0) tok = START_ID;
        else { tok = tgt[b * T + (t - 1)]; if (tok >= V) tok = UNK_ID; }
        xr[r][e] = emb[(size_t)tok * E + e];
    }
    __syncthreads();
#pragma unroll
    for (int half = 0; half < 2; half++) {
        int u = tid + half * 256;
        float acc[8][4];
#pragma unroll
        for (int r = 0; r < 8; r++)
#pragma unroll
            for (int g = 0; g < 4; g++) acc[r][g] = 0.f;
#pragma unroll 4
        for (int k = 0; k < E; k++) {
            float4 w = P[k * D + u];
#pragma unroll
            for (int r = 0; r < 8; r++) {
                float x = xr[r][k];
                acc[r][0] += x * w.x; acc[r][1] += x * w.y;
                acc[r][2] += x * w.z; acc[r][3] += x * w.w;
            }
        }
        float b0 = bias[u], b1 = bias[D + u], b2 = bias[2 * D + u], b3 = bias[3 * D + u];
#pragma unroll
        for (int r = 0; r < 8; r++) {
            float* g = G + (size_t)(n0 + r) * (4 * D);
            g[u] = acc[r][0] + b0; g[D + u] = acc[r][1] + b1;
            g[2 * D + u] = acc[r][2] + b2; g[3 * D + u] = acc[r][3] + b3;
        }
    }
}

// ---- dec LAYER-0 standalone scan (dataflow). blk in [0,32). smem >= 20992.
// Step t: poll h0[t-1] (tag t+1), 16 MFMA, cell, publish h0[t] (tag t+2) + plain h0bf.
__device__ __forceinline__ void decL0_body(int bk, char* smem,
        const float* __restrict__ G0, const ushort* __restrict__ PM0,
        uint* __restrict__ h0pk, ushort* __restrict__ h0bf) {
    ushort* hb = (ushort*)smem;                              // 16*520*2 = 16640 B
    float (*gs)[16][17] = (float(*)[16][17])(smem + 16640);  // 4352 B
    int tid = threadIdx.x;
    int lane = tid & 63, w = tid >> 6;
    int cl = lane & 15, hi = lane >> 4;
    short8 a0[16];
    {
        const ushort* base0 = PM0 + (size_t)(bk * 64 + w * 16 + cl) * 512 + hi * 8;
#pragma unroll
        for (int kt = 0; kt < 16; kt++) a0[kt] = *(const short8*)(base0 + kt * 32);
    }
    int u_loc = tid & 15, b = tid >> 4;
    int u = bk * 16 + u_loc;
    float c0v = 0.f;
    int sb = tid >> 4, kseg = tid & 15;
    int sflat = sb * 512 + kseg * 32;

    for (int t = 0; t < T; t++) {
        poll_stage32(h0pk + ((t + 1) & 1) * 8192 + sflat, (uint)(t + 1) & 0xffffu,
                     hb + sb * 520 + kseg * 32);
        __syncthreads();
        {
            f32x4 acc = {0.f, 0.f, 0.f, 0.f};
            const ushort* hp = hb + cl * 520 + hi * 8;
#pragma unroll
            for (int kt = 0; kt < 16; kt++) {
                short8 bfr = *(const short8*)(hp + kt * 32);
                acc = __builtin_amdgcn_mfma_f32_16x16x32_bf16(a0[kt], bfr, acc, 0, 0, 0);
            }
#pragma unroll
            for (int i = 0; i < 4; i++) gs[w][hi * 4 + i][cl] = acc[i];
        }
        __syncthreads();
        {
            const float* gg = G0 + ((size_t)(t * B + b)) * 2048 + u;
            float g0 = gg[0]    + gs[0][u_loc][b];
            float g1 = gg[512]  + gs[1][u_loc][b];
            float g2 = gg[1024] + gs[2][u_loc][b];
            float g3 = gg[1536] + gs[3][u_loc][b];
            float ig = sigm(g0), fg = sigm(g1), gt = tanhf(g2), og = sigm(g3);
            c0v = fg * c0v + ig * gt;
            float h0n = og * tanhf(c0v);
            ushort hb16 = (ushort)bf16s(h0n);
            pstore(&h0pk[(t & 1) * 8192 + b * 512 + u],
                   ((uint)hb16 << 16) | ((uint)(t + 2) & 0xffffu));
            h0bf[(size_t)t * 8192 + b * 512 + u] = hb16;
        }
        __syncthreads();
    }
}

// ---- dec LAYER-1 scan: h0 from plain-loaded h0bf; h1 via packets. blk in [0,32).
__device__ __forceinline__ void decL1_body(int bk, char* smem,
        const ushort* __restrict__ PM1, const float* __restrict__ b1,
        const ushort* __restrict__ h0bf, uint* __restrict__ h1pk,
        float* __restrict__ h1out) {
    ushort* hb = (ushort*)smem;                              // 16*1032*2 = 33024 B
    float (*gs)[16][17] = (float(*)[16][17])(smem + 33024);  // 4352 B
    int tid = threadIdx.x;
    int lane = tid & 63, w = tid >> 6;
    int cl = lane & 15, hi = lane >> 4;
    short8 a1[32];
    {
        const ushort* base1 = PM1 + (size_t)(bk * 64 + w * 16 + cl) * 1024 + hi * 8;
#pragma unroll
        for (int kt = 0; kt < 32; kt++) a1[kt] = *(const short8*)(base1 + kt * 32);
    }
    int u_loc = tid & 15, b = tid >> 4;
    int u = bk * 16 + u_loc;
    float bi0 = b1[u], bi1 = b1[512 + u], bi2 = b1[1024 + u], bi3 = b1[1536 + u];
    float c1v = 0.f;
    int sb = tid >> 4, kseg = tid & 15;
    int sflat = sb * 512 + kseg * 32;

    for (int t = 0; t < T; t++) {
        // stage h0[t] (plain cached loads — fully materialized by decL0 kernel)
        {
            const short8* src = (const short8*)(h0bf + (size_t)t * 8192 + sflat);
            short8 v0 = src[0], v1 = src[1], v2 = src[2], v3 = src[3];
            short8* dst = (short8*)(hb + sb * 1032 + kseg * 32);
            dst[0] = v0; dst[1] = v1; dst[2] = v2; dst[3] = v3;
        }
        poll_stage32(h1pk + ((t + 1) & 1) * 8192 + sflat, (uint)(t + 1) & 0xffffu,
                     hb + sb * 1032 + 512 + kseg * 32);
        __syncthreads();
        {
            f32x4 acc = {0.f, 0.f, 0.f, 0.f};
            const ushort* hp = hb + cl * 1032 + hi * 8;
#pragma unroll
            for (int kt = 0; kt < 32; kt++) {
                short8 bfr = *(const short8*)(hp + kt * 32);
                acc = __builtin_amdgcn_mfma_f32_16x16x32_bf16(a1[kt], bfr, acc, 0, 0, 0);
            }
#pragma unroll
            for (int i = 0; i < 4; i++) gs[w][hi * 4 + i][cl] = acc[i];
        }
        __syncthreads();
        {
            float g0 = bi0 + gs[0][u_loc][b];
            float g1 = bi1 + gs[1][u_loc][b];
            float g2 = bi2 + gs[2][u_loc][b];
            float g3 = bi3 + gs[3][u_loc][b];
            float ig = sigm(g0), fg = sigm(g1), gt = tanhf(g2), og = sigm(g3);
            c1v = fg * c1v + ig * gt;
            float h1n = og * tanhf(c1v);
            pstore(&h1pk[(t & 1) * 8192 + b * 512 + u],
                   ((uint)(ushort)bf16s(h1n) << 16) | ((uint)(t + 2) & 0xffffu));
            h1out[((size_t)(t * B + b)) * 512 + u] = h1n;
        }
        __syncthreads();
    }
}

// ---- enchB pack: [b][o(d/8)=64][s(512)][8d]
__device__ __forceinline__ void encht2_body(int bid,
        const float* __restrict__ h1f, const float* __restrict__ h1b,
        ushort* __restrict__ enchB) {
    int idx = bid * 256 + threadIdx.x;
    int b = idx >> 15;
    int r = idx & 32767;
    int o = r >> 9, s = r & 511;
    const float* src = (o < 32) ? (h1f + ((size_t)(s * B + b)) * H + o * 8)
                                : (h1b + ((size_t)(s * B + b)) * H + (o - 32) * 8);
    float4 v0 = *(const float4*)src, v1 = *(const float4*)(src + 4);
    st_bf8(enchB + ((size_t)b << 18) + o * 4096 + s * 8, v0, v1);
}

// ---- enchT pack: [b][o(s/8)=64][d(512)][8s]
__device__ __forceinline__ void encht2T_body(int bid,
        const float* __restrict__ h1f, const float* __restrict__ h1b,
        ushort* __restrict__ enchT) {
    int idx = bid * 256 + threadIdx.x;
    int b = idx >> 15;
    int r = idx & 32767;
    int o = r >> 9, d = r & 511;
    float f[8];
#pragma unroll
    for (int j = 0; j < 8; j++) {
        int s = o * 8 + j;
        f[j] = (d < H) ? h1f[((size_t)(s * B + b)) * H + d]
                       : h1b[((size_t)(s * B + b)) * H + (d - H)];
    }
    float4 v0 = {f[0], f[1], f[2], f[3]}, v1 = {f[4], f[5], f[6], f[7]};
    st_bf8(enchT + ((size_t)b << 18) + o * 4096 + d * 8, v0, v1);
}

// ---- out_proj body
__device__ __forceinline__ void outproj_body(int bid, char* smem,
        const float* __restrict__ emb, const float* __restrict__ Wvoc,
        __hip_bfloat16* __restrict__ outT2) {
    float (*er)[E + 1] = (float(*)[E + 1])smem;
    int j0 = bid * 32;
    int jl = threadIdx.x & 31, oq = threadIdx.x >> 5;
    for (int i = threadIdx.x; i < 32 * E; i += 256) {
        int jj = i >> 7, e = i & 127;
        int j = j0 + jj;
        er[jj][e] = (j < VO) ? emb[(size_t)(3 + j) * E + e] : 0.f;
    }
    __syncthreads();
    int j = j0 + jl;
#pragma unroll 1
    for (int i = 0; i < 24; i++) {
        int o = oq * 24 + i;
        int k0 = o * 8;
        float acc[8];
#pragma unroll
        for (int kk = 0; kk < 8; kk++) acc[kk] = 0.f;
#pragma unroll 4
        for (int e = 0; e < E; e++) {
            float x = er[jl][e];
            float4 w0 = *(const float4*)(Wvoc + (size_t)e * C3 + k0);
            float4 w1 = *(const float4*)(Wvoc + (size_t)e * C3 + k0 + 4);
            acc[0] += x * w0.x; acc[1] += x * w0.y; acc[2] += x * w0.z; acc[3] += x * w0.w;
            acc[4] += x * w1.x; acc[5] += x * w1.y; acc[6] += x * w1.z; acc[7] += x * w1.w;
        }
        short8 v;
#pragma unroll
        for (int kk = 0; kk < 8; kk++) v[kk] = bf16s(tanhf(acc[kk]));
        *reinterpret_cast<short8*>((char*)outT2 + ((size_t)o * JS + j) * 16) = v;
    }
}

// ---- generic MFMA "A-in-regs @ streamed B" body (wave-uniform LDS staging).
template<int NF, int TILES, int OSTR, bool DOEXP>
__device__ __forceinline__ void gemm16_body(char* smem,
        const ushort* __restrict__ Abase, int arow_stride,
        const ushort* __restrict__ Bsrc, float* __restrict__ outbase,
        int out_stride) {
    ushort* Bs = (ushort*)smem;
    const int CH = NF * 64;
    const int NG = CH / 64;
    int tid = threadIdx.x;
    int lane = tid & 63, w = tid >> 6;
    int cl = lane & 15, hi = lane >> 4;
    short8 a[NF];
    {
        const ushort* asrc = Abase + (size_t)(w * 16 + cl) * arow_stride + hi * 8;
#pragma unroll
        for (int kt = 0; kt < NF; kt++) a[kt] = *(const short8*)(asrc + kt * 32);
    }
    for (int g = w; g < NG; g += 8) {
        int c = g * 64 + lane;
        int o = c >> 4, jl = c & 15;
        gload_lds16(Bsrc + ((size_t)o * OSTR + jl) * 8,
                    (char*)Bs + (size_t)(g * 64) * 16);
    }
    asm volatile("s_waitcnt vmcnt(0)" ::: "memory");
    __syncthreads();
    int buf = 0;
    for (int t = 0; t < TILES; t++) {
        if (t + 1 < TILES) {
            for (int g = w; g < NG; g += 8) {
                int c = g * 64 + lane;
                int o = c >> 4, jl = c & 15;
                gload_lds16(Bsrc + ((size_t)o * OSTR + (t + 1) * 16 + jl) * 8,
                            (char*)Bs + (size_t)((buf ^ 1) * CH + g * 64) * 16);
            }
        }
        f32x4 acc = {0.f, 0.f, 0.f, 0.f};
        const ushort* bp = Bs + (size_t)buf * CH * 8 + (size_t)(hi * 16 + cl) * 8;
#pragma unroll
        for (int kt = 0; kt < NF; kt++) {
            short8 b = *(const short8*)(bp + (size_t)kt * 512);
            acc = __builtin_amdgcn_mfma_f32_16x16x32_bf16(a[kt], b, acc, 0, 0, 0);
        }
#pragma unroll
        for (int i = 0; i < 4; i++) {
            int row = w * 16 + hi * 4 + i;
            float v = acc[i];
            if (DOEXP) v = __expf(fminf(v, 30.0f));
            outbase[(size_t)row * out_stride + t * 16 + cl] = v;
        }
        asm volatile("s_waitcnt vmcnt(0)" ::: "memory");
        __syncthreads();
        buf ^= 1;
    }
}

// ================= mega-kernels =================

// megaA: 0..15 enc L0 scan; 16..271 dec0 gates.
__global__ void __launch_bounds__(256) megaA(
        const float* Gf, const float* Gb, const ushort* PMf, const ushort* PMb,
        float* hof, float* hob, float* hfin, uint* pk,
        const int* tgt, const float* emb, const float4* PdW, const float* dbias,
        float* Gd0) {
    __shared__ __align__(16) char smem[17152];
    int blk = blockIdx.x;
    if (blk < 16) enc_scan_body(blk, smem, Gf, Gb, PMf, PMb, hof, hob, hfin, pk);
    else dec0_body(blk - 16, smem, tgt, emb, PdW, dbias, Gd0);
}

// megaB2: 0..15 enc L1 scan; 16..47 dec layer-0 scan; 48..79 h0-init publish.
__global__ void __launch_bounds__(256) megaB2(
        const float* Gf, const float* Gb, const ushort* PMf, const ushort* PMb,
        float* hof, float* hob, float* hfin, uint* pkE,
        const float* Gd0, const ushort* PM0, uint* h0pk, ushort* h0bf,
        const float* hinit) {
    __shared__ __align__(16) char smem[20992];
    int blk = blockIdx.x;
    if (blk < 16) enc_scan_body(blk, smem, Gf, Gb, PMf, PMb, hof, hob, hfin, pkE);
    else if (blk < 48) decL0_body(blk - 16, smem, Gd0, PM0, h0pk, h0bf);
    else {
        int idx = (blk - 48) * 256 + threadIdx.x;     // B*D = 8192
        pstore(&h0pk[8192 + idx],
               ((uint)(ushort)bf16s(hinit[idx]) << 16) | 1u);
    }
}

// megaC2: 0..31 dec L1 scan; 32..63 h1-init publish; 64..2111 enchB;
// 2112..4159 enchT; 4160..5159 outproj.
__global__ void __launch_bounds__(256) megaC2(
        const ushort* PM1, const float* b1, const ushort* h0bf,
        uint* h1pk, float* h1out, const float* hinit,
        const float* h1f, const float* h1b, ushort* enchB, ushort* enchT,
        const float* emb, const float* Wvoc, __hip_bfloat16* outT2) {
    __shared__ __align__(16) char smem[37376];
    int blk = blockIdx.x;
    if (blk < 32) decL1_body(blk, smem, PM1, b1, h0bf, h1pk, h1out);
    else if (blk < 64) {
        int idx = (blk - 32) * 256 + threadIdx.x;
        pstore(&h1pk[8192 + idx],
               ((uint)(ushort)bf16s(hinit[B * D + idx]) << 16) | 1u);
    }
    else if (blk < 2112) encht2_body(blk - 64, h1f, h1b, enchB);
    else if (blk < 4160) encht2T_body(blk - 2112, h1f, h1b, enchT);
    else outproj_body(blk - 4160, smem, emb, Wvoc, outT2);
}

// ---------------- q projections: bf16 qe, bf16 qd, h1dB1 pack. grid T*B, 512 thr.
__global__ void qproj(const float* __restrict__ h1d, const float* __restrict__ Wenc,
                      const float* __restrict__ Wdec, ushort* __restrict__ qeb16,
                      ushort* __restrict__ qdb16, ushort* __restrict__ h1dB1) {
    int n = blockIdx.x;
    int o = threadIdx.x;
    __shared__ float hr[D];
    hr[o] = h1d[(size_t)n * D + o];
    __syncthreads();
    float ae = 0.f, ad = 0.f;
#pragma unroll 4
    for (int k = 0; k < D; k++) {
        float hk = hr[k];
        ae += hk * Wenc[k * D + o];
        ad += hk * Wdec[k * D + o];
    }
    int b = n & 15, t = n >> 4;
    size_t rowb = (size_t)(b * 128 + t) << 9;
    qeb16[rowb + o] = (ushort)bf16s(ae);
    qdb16[rowb + o] = (ushort)bf16s(ad);
    if (o < 64) {
        float4 v0 = *(const float4*)(hr + o * 8);
        float4 v1 = *(const float4*)(hr + o * 8 + 4);
        st_bf8(h1dB1 + ((size_t)b << 16) + o * 1024 + t * 8, v0, v1);
    }
}

// ---------------- h1dB2 pack: [b][o(u/8)=16][d(512)][8u]. grid 512, 256 thr.
__global__ void pack_h1dB2(const float* __restrict__ h1d, ushort* __restrict__ h1dB2) {
    int idx = blockIdx.x * 256 + threadIdx.x;
    int b = idx >> 13;
    int r = idx & 8191;
    int o = r >> 9, d = r & 511;
    float f[8];
#pragma unroll
    for (int j = 0; j < 8; j++)
        f[j] = h1d[((size_t)((o * 8 + j) * B + b)) * D + d];
    float4 v0 = {f[0], f[1], f[2], f[3]}, v1 = {f[4], f[5], f[6], f[7]};
    st_bf8(h1dB2 + ((size_t)b << 16) + o * 4096 + d * 8, v0, v1);
}

// ---------------- scoreAB: blk<16 escore (ew, fused exp); else dec QK^T (dsout).
__global__ void __launch_bounds__(512) scoreAB(
        const ushort* __restrict__ qeb16, const ushort* __restrict__ enchB,
        float* __restrict__ ew,
        const ushort* __restrict__ qdb16, const ushort* __restrict__ h1dB1,
        float* __restrict__ dsout) {
    __shared__ __align__(16) char smem[32768];
    int blk = blockIdx.x;
    if (blk < 16) {
        int b = blk;
        gemm16_body<16, 32, 512, true>(smem,
            qeb16 + ((size_t)(b * 128) << 9), 512,
            enchB + ((size_t)b << 18),
            ew + (size_t)b * T * S, S);
    } else {
        int b = blk - 16;
        gemm16_body<16, 8, 128, false>(smem,
            qdb16 + ((size_t)(b * 128) << 9), 512,
            h1dB1 + ((size_t)b << 16),
            dsout + ((size_t)(b * 128)) * 128, 128);
    }
}

// ---------------- temporal normalization (prefix over t)
__global__ void temporal_k(float* __restrict__ ew) {
    int i = blockIdx.x * blockDim.x + threadIdx.x;
    if (i >= B * S) return;
    int b = i / S, sx = i - b * S;
    float cum = 0.f;
    for (int t = 0; t < T; t++) {
        size_t idx = ((size_t)(b * T + t)) * S + sx;
        float v = ew[idx];
        ew[idx] = v / (t == 0 ? 1.0f : (cum + 1e-8f));
        cum += v;
    }
}

// ---------------- smAB: blk<2048 enc softmax+copy (awb16); else dec softmax (pdb16).
__global__ void __launch_bounds__(512) smAB(
        const float* __restrict__ ew, const int* __restrict__ ids,
        const int* __restrict__ tgt, ushort* __restrict__ awb16,
        float* __restrict__ copyp,
        const float* __restrict__ dsout, ushort* __restrict__ pdb16) {
    __shared__ float red[512];
    int blk = blockIdx.x;
    int tid = threadIdx.x;
    if (blk < 2048) {
        int bt = blk;
        int b = bt >> 7, t = bt & 127;
        float v = ew[(size_t)bt * S + tid];
        int tok = ids[b * S + tid];
        bool pad = (tok == PAD_ID);
        float vm = pad ? -INFINITY : v;
        red[tid] = vm; __syncthreads();
        for (int w = 256; w > 0; w >>= 1) { if (tid < w) red[tid] = fmaxf(red[tid], red[tid + w]); __syncthreads(); }
        float m = red[0]; __syncthreads();
        float ex = pad ? 0.f : __expf(vm - m);
        red[tid] = ex; __syncthreads();
        for (int w = 256; w > 0; w >>= 1) { if (tid < w) red[tid] += red[tid + w]; __syncthreads(); }
        float Z = red[0]; __syncthreads();
        float a = ex / Z;
        int nt = tgt[b * T + t];
        red[tid] = (tok == nt) ? a : 0.f; __syncthreads();
        for (int w = 256; w > 0; w >>= 1) { if (tid < w) red[tid] += red[tid + w]; __syncthreads(); }
        if (tid == 0) copyp[bt] = red[0];
        awb16[(size_t)bt * S + tid] = (ushort)bf16s(a);
    } else {
        int bt2 = blk - 2048;
        int t = bt2 & 127;
        float sc = -INFINITY;
        if (tid < 128 && tid < t) sc = dsout[(size_t)bt2 * 128 + tid];
        if (tid < 128) red[tid] = sc;
        __syncthreads();
        for (int w = 64; w > 0; w >>= 1) { if (tid < w) red[tid] = fmaxf(red[tid], red[tid + w]); __syncthreads(); }
        float m = red[0]; __syncthreads();
        float ex = (tid < 128 && tid < t) ? __expf(sc - m) : 0.f;
        if (tid < 128) red[tid] = ex;
        __syncthreads();
        for (int w = 64; w > 0; w >>= 1) { if (tid < w) red[tid] += red[tid + w]; __syncthreads(); }
        float Z = red[0];
        if (tid < 128) pdb16[(size_t)bt2 * 128 + tid] = (ushort)bf16s((t > 0) ? ex / Z : 0.f);
    }
}

// ---------------- ctxAB: blk<16 ectx = aw @ ench; else dctx = P @ h1d.
__global__ void __launch_bounds__(512) ctxAB(
        const ushort* __restrict__ awb16, const ushort* __restrict__ enchT,
        float* __restrict__ ectx,
        const ushort* __restrict__ pdb16, const ushort* __restrict__ h1dB2,
        float* __restrict__ dctx) {
    __shared__ __align__(16) char smem[32768];
    int blk = blockIdx.x;
    if (blk < 16) {
        int b = blk;
        gemm16_body<16, 32, 512, false>(smem,
            awb16 + ((size_t)(b * 128)) * 512, 512,
            enchT + ((size_t)b << 18),
            ectx + ((size_t)(b * 128)) * 512, 512);
    } else {
        int b = blk - 16;
        gemm16_body<4, 32, 512, false>(smem,
            pdb16 + ((size_t)(b * 128)) * 128, 128,
            h1dB2 + ((size_t)b << 16),
            dctx + ((size_t)(b * 128)) * 512, 512);
    }
}

// ---------------- concat + p_gen; writes bf16 ccb16. grid B*T, 512 thr
__global__ void concat_k(const float* __restrict__ h1d, const float* __restrict__ ectx,
                         const float* __restrict__ dctx, const float* __restrict__ sW,
                         const float* __restrict__ sb, ushort* __restrict__ ccb16,
                         float* __restrict__ pgen) {
    int bt = blockIdx.x;
    int b = bt / T, t = bt - b * T;
    int d = threadIdx.x;
    __shared__ float red[512];
    float v0 = h1d[((size_t)(t * B + b)) * D + d];
    float v1 = ectx[(size_t)bt * D + d];
    float v2 = dctx[(size_t)bt * D + d];
    ushort* c = ccb16 + (size_t)bt * C3;
    c[d] = (ushort)bf16s(v0); c[D + d] = (ushort)bf16s(v1); c[2 * D + d] = (ushort)bf16s(v2);
    red[d] = v0 * sW[d] + v1 * sW[D + d] + v2 * sW[2 * D + d];
    __syncthreads();
    for (int w = 256; w > 0; w >>= 1) { if (d < w) red[d] += red[d + w]; __syncthreads(); }
    if (d == 0) pgen[bt] = 1.f / (1.f + __expf(-(red[0] + sb[0])));
}

// ---------------- vocab GEMM: register-A (M=128), LDS dbuf B stream (passing).
__global__ void __launch_bounds__(512) vocab_mfma3(
        const __hip_bfloat16* __restrict__ outT2, const ushort* __restrict__ ccb16,
        const float* __restrict__ ob, const int* __restrict__ tgt,
        float* __restrict__ pbuf) {
    __shared__ __align__(16) ushort Bs[2][3072 * 8];
    __shared__ int jstar_s[128];
    int bid = blockIdx.x;
    int rb = bid & 15, jg = bid >> 4;
    int row0 = rb * 128;
    int tid = threadIdx.x;
    int lane = tid & 63, w = tid >> 6;
    int cl = lane & 15, hi = lane >> 4;
    int j0base = jg * 2000;

    if (tid < 128) {
        int nt = tgt[row0 + tid];
        int ix = nt - 3;
        ix = ix < 0 ? 0 : (ix > VO - 1 ? VO - 1 : ix);
        jstar_s[tid] = ix;
    }
    short8 a[48];
    {
        const ushort* asrc = ccb16 + (size_t)(row0 + w * 16 + cl) * C3 + hi * 8;
#pragma unroll
        for (int kt = 0; kt < 48; kt++) a[kt] = *(const short8*)(asrc + kt * 32);
    }
    {
#pragma unroll
        for (int ii = 0; ii < 6; ii++) {
            int c = w * 384 + ii * 64 + lane;
            int o = c >> 4, jl = c & 15;
            const char* g = (const char*)outT2 + ((size_t)o * JS + (size_t)(j0base + jl)) * 16;
            gload_lds16(g, (char*)&Bs[0][0] + (size_t)(w * 384 + ii * 64) * 16);
        }
    }
    asm volatile("s_waitcnt vmcnt(0)" ::: "memory");
    __syncthreads();
    int jst[4];
    float m[4], sacc[4], gl[4];
#pragma unroll
    for (int i = 0; i < 4; i++) {
        jst[i] = jstar_s[w * 16 + hi * 4 + i];
        m[i] = -1e30f; sacc[i] = 0.f; gl[i] = -1e30f;
    }
    int buf = 0;
    for (int t = 0; t < 125; t++) {
        if (t + 1 < 125) {
            int j0 = j0base + (t + 1) * 16;
#pragma unroll
            for (int ii = 0; ii < 6; ii++) {
                int c = w * 384 + ii * 64 + lane;
                int o = c >> 4, jl = c & 15;
                const char* g = (const char*)outT2 + ((size_t)o * JS + (size_t)(j0 + jl)) * 16;
                gload_lds16(g, (char*)&Bs[buf ^ 1][0] + (size_t)(w * 384 + ii * 64) * 16);
            }
        }
        f32x4 acc = {0.f, 0.f, 0.f, 0.f};
        const ushort* bp = &Bs[buf][0] + (size_t)(hi * 16 + cl) * 8;
#pragma unroll
        for (int kt = 0; kt < 48; kt++) {
            short8 b = *(const short8*)(bp + (size_t)kt * 512);
            acc = __builtin_amdgcn_mfma_f32_16x16x32_bf16(a[kt], b, acc, 0, 0, 0);
        }
        int j = j0base + t * 16 + cl;
        bool valid = j < VO;
        float obj = valid ? ob[j] : 0.f;
#pragma unroll
        for (int i = 0; i < 4; i++) {
            float L = acc[i] + obj;
            if (valid) {
                if (j == jst[i]) gl[i] = L;
                float mn = fmaxf(m[i], L);
                sacc[i] = sacc[i] * __expf(m[i] - mn) + __expf(L - mn);
                m[i] = mn;
            }
        }
        asm volatile("s_waitcnt vmcnt(0)" ::: "memory");
        __syncthreads();
        buf ^= 1;
    }
#pragma unroll
    for (int i = 0; i < 4; i++) {
        for (int mask = 1; mask < 16; mask <<= 1) {
            float om = __shfl_xor(m[i], mask);
            float os = __shfl_xor(sacc[i], mask);
            float mn = fmaxf(m[i], om);
            sacc[i] = sacc[i] * __expf(m[i] - mn) + os * __expf(om - mn);
            m[i] = mn;
            gl[i] = fmaxf(gl[i], __shfl_xor(gl[i], mask));
        }
    }
    if (cl == 0) {
#pragma unroll
        for (int i = 0; i < 4; i++) {
            int rl = w * 16 + hi * 4 + i;
            float* o = pbuf + ((size_t)(jg * 16 + rb) * 128 + rl) * 4;
            o[0] = m[i]; o[1] = sacc[i]; o[2] = gl[i];
        }
    }
}

// ---------------- combine 16 jg-partials + pointer mix + NLL. grid B, 128 threads.
__global__ void combine_nll_k(const float* __restrict__ pbuf, const int* __restrict__ tgt,
                              const float* __restrict__ pgen, const float* __restrict__ copyp,
                              const int* __restrict__ tlen, float* __restrict__ out) {
    int b = blockIdx.x, t = threadIdx.x;
    int row = b * T + t;
    int rb = row >> 7, rl = row & 127;
    float M = -1e30f, SS = 0.f, GL = -1e30f;
#pragma unroll
    for (int q = 0; q < 16; q++) {
        const float* p = pbuf + ((size_t)(q * 16 + rb) * 128 + rl) * 4;
        float mq = p[0], sq = p[1], gq = p[2];
        float mn = fmaxf(M, mq);
        SS = SS * __expf(M - mn) + sq * __expf(mq - mn);
        M = mn;
        GL = fmaxf(GL, gq);
    }
    int nt = tgt[row];
    float genp = (nt >= 3 && nt < V) ? __expf(GL - M) / SS : 0.f;
    float pg = pgen[row];
    float p = pg * genp + (1.f - pg) * copyp[row];
    __shared__ float red[128];
    red[t] = (t < tlen[b]) ? -logf(p + 1e-9f) : 0.f;
    __syncthreads();
    for (int w = 64; w > 0; w >>= 1) { if (t < w) red[t] += red[t + w]; __syncthreads(); }
    if (t == 0) out[b] = red[0];
}

extern "C" void kernel_launch(void* const* d_in, const int* in_sizes, int n_in,
                              void* d_out, int out_size, void* d_ws, size_t ws_size,
                              hipStream_t stream) {
    const int* input_ids = (const int*)d_in[0];
    const int* target_ids = (const int*)d_in[1];
    const int* tlen = (const int*)d_in[3];
    const float* emb = (const float*)d_in[5];
    const float* eWih0f = (const float*)d_in[6],  *eWhh0f = (const float*)d_in[7],  *eb0f = (const float*)d_in[8];
    const float* eWih0b = (const float*)d_in[9],  *eWhh0b = (const float*)d_in[10], *eb0b = (const float*)d_in[11];
    const float* eWih1f = (const float*)d_in[12], *eWhh1f = (const float*)d_in[13], *eb1f = (const float*)d_in[14];
    const float* eWih1b = (const float*)d_in[15], *eWhh1b = (const float*)d_in[16], *eb1b = (const float*)d_in[17];
    const float* dWih0 = (const float*)d_in[18], *dWhh0 = (const float*)d_in[19], *db0 = (const float*)d_in[20];
    const float* dWih1 = (const float*)d_in[21], *dWhh1 = (const float*)d_in[22], *db1 = (const float*)d_in[23];
    const float* Wenc = (const float*)d_in[24], *Wdec = (const float*)d_in[25];
    const float* Wvoc = (const float*)d_in[26], *sW = (const float*)d_in[27], *sb = (const float*)d_in[28];
    const float* ob = (const float*)d_in[29];
    float* out = (float*)d_out;
    (void)ws_size; (void)n_in; (void)in_sizes; (void)out_size;

    // ============ workspace layout (~195.5 MB, phase-aliased) ============
    char* A = (char*)d_ws;
    float4* pWih0f = (float4*)(A + 0);
    float4* pWih0b = (float4*)(A + 524288);
    ushort* PMW1f  = (ushort*)(A + 1048576);
    ushort* PMW1b  = (ushort*)(A + 2097152);
    float4* pdWih0 = (float4*)(A + 5242880);
    ushort* PMf0  = (ushort*)(A + 6291456);
    ushort* PMb0  = (ushort*)(A + 6815744);
    ushort* PMf1  = (ushort*)(A + 7340032);
    ushort* PMb1  = (ushort*)(A + 7864320);
    float* G0f = (float*)(A + 23068672);
    float* G0b = (float*)(A + 56623104);
    __hip_bfloat16* outT2 = (__hip_bfloat16*)A;     // whole region (megaC2)

    char* Bh = A + 98304000;
    float* h0f = (float*)(Bh + 0);
    float* h0b = (float*)(Bh + 8388608);
    float* h1d = (float*)(Bh + 0);
    ushort* qeb16 = (ushort*)(Bh + 4194304);
    ushort* awb16 = (ushort*)(Bh + 6291456);
    ushort* qdb16 = (ushort*)(Bh + 8388608);
    ushort* h1dB1 = (ushort*)(Bh + 10485760);
    float* ew  = (float*)(Bh + 12582912);
    float* pbuf = (float*)(Bh + 12582912);

    char* Cr = Bh + 16777216;
    float* h1f = (float*)(Cr + 0);
    float* h1b = (float*)(Cr + 8388608);
    ushort* ccb16 = (ushort*)(Cr + 16777216);
    float*  dsout = (float*)(Cr + 23068672);
    ushort* pdb16 = (ushort*)(Cr + 24117248);
    ushort* h1dB2 = (ushort*)(Cr + 24641536);
    float* dec_init = (float*)(Cr + 29360128);
    float* pgen  = (float*)(Cr + 29425664);
    float* copyp = (float*)(Cr + 29433856);
    uint* hpkE0  = (uint*)(Cr + 29769728);
    uint* hpkE1  = (uint*)(Cr + 29835264);
    uint* h0pkD  = (uint*)(Cr + 29900800);
    uint* h1pkD  = (uint*)(Cr + 29966336);

    char* X = Cr + 30031872;
    float*  Gd0x  = (float*)(X + 0);                // 16,777,216
    ushort* PM0x  = (ushort*)(X + 16777216);        // 2,097,152
    ushort* PM1x  = (ushort*)(X + 18874368);        // 4,194,304
    ushort* enchB = (ushort*)(X + 23068672);        // 8,388,608
    float*  ectx  = (float*)(X + 31457280);         // 4,194,304
    float*  dctx  = (float*)(X + 35651584);         // 4,194,304
    ushort* enchT = (ushort*)(X + 39845888);        // 8,388,608
    ushort* h0bf  = (ushort*)(X + 48234496);        // 2,097,152 (dec L0 bf16 outputs)
    // total ≈ 195,445,504 B

    hipMemsetAsync(hpkE0, 0, 262144, stream);

    auto pack = [&](const float* W, float4* P, int Hn, int K) {
        int total = Hn * K;
        hipLaunchKernelGGL(pack4_kernel, dim3((total + 255) / 256), dim3(256), 0, stream, W, P, Hn, K);
    };
    pack(eWih0f, pWih0f, H, E);
    pack(eWih0b, pWih0b, H, E);
    pack(dWih0, pdWih0, D, E);
    hipLaunchKernelGGL(packencMK_k, dim3(4 * H * 256 / 256), dim3(256), 0, stream, eWhh0f, PMf0, 256);
    hipLaunchKernelGGL(packencMK_k, dim3(4 * H * 256 / 256), dim3(256), 0, stream, eWhh0b, PMb0, 256);
    hipLaunchKernelGGL(packencMK_k, dim3(4 * H * 256 / 256), dim3(256), 0, stream, eWhh1f, PMf1, 256);
    hipLaunchKernelGGL(packencMK_k, dim3(4 * H * 256 / 256), dim3(256), 0, stream, eWhh1b, PMb1, 256);
    hipLaunchKernelGGL(packencMK_k, dim3(4 * H * 512 / 256), dim3(256), 0, stream, eWih1f, PMW1f, 512);
    hipLaunchKernelGGL(packencMK_k, dim3(4 * H * 512 / 256), dim3(256), 0, stream, eWih1b, PMW1b, 512);
    hipLaunchKernelGGL(packdecM_k, dim3(4 * D * D / 256), dim3(256), 0, stream, dWhh0, PM0x);
    hipLaunchKernelGGL(packdecM2_k, dim3(8 * D * D / 256), dim3(256), 0, stream, dWih1, dWhh1, PM1x);

    hipLaunchKernelGGL(enc0_gates2, dim3(S * B / 8), dim3(256), 0, stream,
                       input_ids, emb, pWih0f, eb0f, pWih0b, eb0b, G0f, G0b);
    // megaA: enc L0 scan + dec0 gates (writes dec_init L0 finals at end)
    hipLaunchKernelGGL(megaA, dim3(272), dim3(256), 0, stream,
                       G0f, G0b, PMf0, PMb0, h0f, h0b, dec_init, hpkE0,
                       target_ids, emb, pdWih0, db0, Gd0x);
    hipLaunchKernelGGL(enc1g_mfma, dim3(256), dim3(256), 0, stream,
                       h0f, h0b, PMW1f, PMW1b, eb1f, eb1b, G0f, G0b);
    // megaB2: enc L1 scan || dec layer-0 scan (hidden) || h0-init publish
    hipLaunchKernelGGL(megaB2, dim3(80), dim3(256), 0, stream,
                       G0f, G0b, PMf1, PMb1, h1f, h1b, dec_init + B * D, hpkE1,
                       Gd0x, PM0x, h0pkD, h0bf, dec_init);
    // megaC2: dec layer-1 scan + h1-init publish + enchB/enchT/outproj
    hipLaunchKernelGGL(megaC2, dim3(5160), dim3(256), 0, stream,
                       PM1x, db1, h0bf, h1pkD, h1d, dec_init,
                       h1f, h1b, enchB, enchT, emb, Wvoc, outT2);
    hipLaunchKernelGGL(qproj, dim3(T * B), dim3(D), 0, stream,
                       h1d, Wenc, Wdec, qeb16, qdb16, h1dB1);
    hipLaunchKernelGGL(pack_h1dB2, dim3(512), dim3(256), 0, stream, h1d, h1dB2);
    hipLaunchKernelGGL(scoreAB, dim3(32), dim3(512), 0, stream,
                       qeb16, enchB, ew, qdb16, h1dB1, dsout);
    hipLaunchKernelGGL(temporal_k, dim3((B * S + 255) / 256), dim3(256), 0, stream, ew);
    hipLaunchKernelGGL(smAB, dim3(4096), dim3(512), 0, stream,
                       ew, input_ids, target_ids, awb16, copyp, dsout, pdb16);
    hipLaunchKernelGGL(ctxAB, dim3(32), dim3(512), 0, stream,
                       awb16, enchT, ectx, pdb16, h1dB2, dctx);
    hipLaunchKernelGGL(concat_k, dim3(B * T), dim3(D), 0, stream,
                       h1d, ectx, dctx, sW, sb, ccb16, pgen);
    hipLaunchKernelGGL(vocab_mfma3, dim3(256), dim3(512), 0, stream,
                       outT2, ccb16, ob, target_ids, pbuf);
    hipLaunchKernelGGL(combine_nll_k, dim3(B), dim3(T), 0, stream,
                       pbuf, target_ids, pgen, copyp, tlen, out);
}